// Round 4
// baseline (447.904 us; speedup 1.0000x reference)
//
#include <hip/hip_runtime.h>
#include <math.h>

// ---------------------------------------------------------------------------
// CODA block on MI355X, fp32. 11 dispatches:
//  gamma(+stats zero), row0(inorm+rowDFT), colF, score(splitK partials),
//  softmax(+DC terms), pmode, pdhat(+amat), icolF, irow_addx, fno0, fno1
// ---------------------------------------------------------------------------

#define EPSV 1e-5f
#define PI2 6.283185307179586f

typedef float2 cf;

__device__ __forceinline__ cf cmul(cf a, cf b){ return make_float2(a.x*b.x - a.y*b.y, a.x*b.y + a.y*b.x); }
__device__ __forceinline__ cf ldc(const float* p){ return make_float2(p[0], p[1]); }
__device__ __forceinline__ void stc(float* p, cf v){ p[0]=v.x; p[1]=v.y; }

__device__ __forceinline__ void init_tw(cf* tw, int N, float dir){
  for (int j = threadIdx.x; j < N; j += blockDim.x){
    float s, c; sincosf(dir * PI2 * (float)j / (float)N, &s, &c);
    tw[j] = make_float2(c, s);
  }
}

// block reduction of two floats; supports up to 1024 threads
__device__ void breduce2(float& a, float& b){
  __shared__ float sha[16], shb[16];
  for (int off = 32; off > 0; off >>= 1){
    a += __shfl_down(a, off, 64);
    b += __shfl_down(b, off, 64);
  }
  int w = threadIdx.x >> 6, lane = threadIdx.x & 63;
  int nw = (blockDim.x + 63) >> 6;
  if (lane == 0){ sha[w] = a; shb[w] = b; }
  __syncthreads();
  if (threadIdx.x == 0){
    for (int i = 1; i < nw; ++i){ a += sha[i]; b += shb[i]; }
    sha[0] = a; shb[0] = b;
  }
  __syncthreads();
  a = sha[0]; b = shb[0];
  __syncthreads();
}

// --------------------------------------------------------------------------
// fused instance-norm + row rfft (kw 0..64), scaled 1/16384. one block/image.
__global__ __launch_bounds__(1024) void k_row0(const float* __restrict__ x, const float* __restrict__ ng,
                                               const float* __restrict__ nb, float* __restrict__ Cw){
  __shared__ float zb[4096];
  __shared__ cf tw[128];
  init_tw(tw, 128, -1.f);
  int n = blockIdx.x;
  const float* im = x + n*16384;
  float s=0.f, s2=0.f;
  for (int i=threadIdx.x;i<16384;i+=1024){ float v=im[i]; s+=v; s2=fmaf(v,v,s2); }
  breduce2(s,s2);
  float m = s*(1.f/16384.f), var = s2*(1.f/16384.f)-m*m;
  float A = rsqrtf(var+EPSV)*ng[0];
  float Bc = nb[0]-m*A;
  for (int q=0;q<4;++q){
    __syncthreads();
    for (int i=threadIdx.x;i<4096;i+=1024) zb[i] = fmaf(im[q*4096+i], A, Bc);
    __syncthreads();
    for (int i=threadIdx.x;i<2080;i+=1024){
      int hl = i/65, kw = i-hl*65;
      float re=0.f, ii=0.f; int idx=0;
      for (int w=0;w<128;++w){
        float v=zb[hl*128+w]; cf t=tw[idx];
        re=fmaf(v,t.x,re); ii=fmaf(v,t.y,ii);
        idx=(idx+kw)&127;
      }
      float* d = Cw + ((n*128 + q*32+hl)*65 + kw)*2;
      d[0]=re*(1.f/16384.f); d[1]=ii*(1.f/16384.f);
    }
  }
}

// full complex 128-point DFT along first axis, 65 cols, dir=+-1; grid (64,17)
__global__ __launch_bounds__(256) void k_fft_col_full(const float* __restrict__ src, float* __restrict__ dst, float dir){
  __shared__ cf col[4][128];
  __shared__ cf tw[128];
  init_tw(tw, 128, dir);
  int n = blockIdx.x, kwb = blockIdx.y*4;
  for (int i=threadIdx.x;i<512;i+=256){
    int kwl=i>>7, h=i&127; int kw=kwb+kwl;
    col[kwl][h] = (kw<65) ? ldc(src + ((n*128+h)*65+kw)*2) : make_float2(0.f,0.f);
  }
  __syncthreads();
  int a = threadIdx.x & 127, base = threadIdx.x >> 7;
  for (int kwl=base; kwl<4; kwl+=2){
    int kw = kwb+kwl; if (kw>=65) continue;
    float re=0.f, im=0.f; int idx=0;
    for (int h=0;h<128;++h){
      cf v=col[kwl][h]; cf t=tw[idx];
      re = fmaf(v.x,t.x,re); re = fmaf(-v.y,t.y,re);
      im = fmaf(v.x,t.y,im); im = fmaf(v.y,t.x,im);
      idx=(idx+a)&127;
    }
    float* d = dst + ((n*128+a)*65+kw)*2; d[0]=re; d[1]=im;
  }
}

// ---- spectral attention-score machinery ----------------------------------
__device__ __forceinline__ cf kq_mode(const float* w, int o, int kh, int kw){
  if (kw < 16){
    if (kh < 16)  return ldc(w + ((o*16+kh)*16+kw)*2);
    if (kh >= 48) return ldc(w + (((32+o)*16+(kh-48))*16+kw)*2);
  }
  return make_float2(0.f,0.f);
}

// gamma[o][m], m over 64x33 grid; also zeroes stats (block 0)
__global__ __launch_bounds__(256) void k_gamma(const float* __restrict__ wQ, const float* __restrict__ wQs,
                      const float* __restrict__ bQs,
                      const float* __restrict__ wK, const float* __restrict__ wKs,
                      const float* __restrict__ bKs,
                      float* __restrict__ gam, float* __restrict__ gcons, float* __restrict__ stats){
  int o = blockIdx.x;
  if (o==0){ for (int i=threadIdx.x;i<512;i+=256) stats[i]=0.f; }
  float sQ=wQs[o], sK=wKs[o];
  for (int m = threadIdx.x; m < 2112; m += 256){
    int kh = m/33, kw = m-kh*33;
    cf g;
    if (kw == 0){
      int mh = (64-kh)&63;
      cf qp = kq_mode(wQ,o,kh,0);  qp.x += sQ;
      cf qm = kq_mode(wQ,o,mh,0);  qm.x += sQ;
      cf qt = make_float2(0.5f*(qp.x+qm.x), 0.5f*(qp.y-qm.y));
      cf kp = kq_mode(wK,o,kh,0);  kp.x += sK;
      cf km = kq_mode(wK,o,mh,0);  km.x += sK;
      cf kt = make_float2(0.5f*(kp.x+km.x), 0.5f*(kp.y-km.y));
      g = make_float2(64.f*(qt.x*kt.x + qt.y*kt.y), 64.f*(qt.y*kt.x - qt.x*kt.y));
    } else if (kw == 32){
      g = make_float2(64.f*sQ*sK, 0.f);
    } else {
      cf q = kq_mode(wQ,o,kh,kw); q.x += sQ;
      cf k = kq_mode(wK,o,kh,kw); k.x += sK;
      g = make_float2(128.f*(q.x*k.x + q.y*k.y), 128.f*(q.y*k.x - q.x*k.y));
    }
    stc(gam + (o*2112+m)*2, g);
  }
  if (threadIdx.x == 0){
    float qt0 = sQ + kq_mode(wQ,o,0,0).x;
    float kt0 = sK + kq_mode(wK,o,0,0).x;
    gcons[o]    = 64.f*bKs[o]*qt0;
    gcons[32+o] = 64.f*bQs[o]*kt0;
    gcons[64+o] = 64.f*bQs[o]*bKs[o];
  }
}

// scoreP[mk][b,o,t,s] = partial sum over m-slice; reads F directly (E gather)
__global__ __launch_bounds__(256) void k_score(const float* __restrict__ F, const float* __restrict__ gam,
                                               float* __restrict__ scoreP){
  __shared__ float2 Esh[88][33];
  __shared__ float2 gsh[88];
  int b = blockIdx.x, o = blockIdx.y, mk = blockIdx.z;
  int m0 = mk*264;
  int t = threadIdx.x >> 3, s4 = (threadIdx.x & 7) << 2;
  float acc0=0.f,acc1=0.f,acc2=0.f,acc3=0.f;
  for (int ck=0; ck<3; ++ck){
    int mc = m0 + ck*88;
    __syncthreads();
    for (int i = threadIdx.x; i < 88*32; i += 256){
      int tt = i/88, j = i - tt*88;
      int m = mc + j;
      int kh = m/33, kw = m - kh*33;
      int fr = kh<32 ? kh : kh+64;
      const float* Fb = F + (b*32+tt)*16640;
      float2 v;
      if (kw < 32) v = *(const float2*)(Fb + (fr*65+kw)*2);
      else {
        int mh = (64-kh)&63;
        int fr2 = mh<32 ? mh : mh+64;
        float2 a = *(const float2*)(Fb + (fr*65+32)*2);
        float2 c = *(const float2*)(Fb + (fr2*65+32)*2);
        v = make_float2(0.5f*(a.x+c.x), 0.5f*(a.y-c.y));
      }
      Esh[j][tt] = v;
    }
    for (int j = threadIdx.x; j < 88; j += 256)
      gsh[j] = *(const float2*)(gam + (o*2112 + mc + j)*2);
    __syncthreads();
    for (int j=0;j<88;++j){
      float2 g = gsh[j];
      float2 Et = Esh[j][t];
      float a  = g.x*Et.x - g.y*Et.y;
      float bb = g.x*Et.y + g.y*Et.x;
      float2 e0=Esh[j][s4], e1=Esh[j][s4+1], e2=Esh[j][s4+2], e3=Esh[j][s4+3];
      acc0 = fmaf(a,e0.x,fmaf(bb,e0.y,acc0));
      acc1 = fmaf(a,e1.x,fmaf(bb,e1.y,acc1));
      acc2 = fmaf(a,e2.x,fmaf(bb,e2.y,acc2));
      acc3 = fmaf(a,e3.x,fmaf(bb,e3.y,acc3));
    }
  }
  float* sp = scoreP + (((mk*2+b)*32+o)*32 + t)*32 + s4;
  sp[0]=acc0; sp[1]=acc1; sp[2]=acc2; sp[3]=acc3;
}

// sum 8 partials + DC-linear terms, softmax over s -> attn
__global__ __launch_bounds__(64) void k_softmax(float* __restrict__ attn, const float* __restrict__ F,
                                                const float* __restrict__ gcons, const float* __restrict__ scoreP){
  int b = blockIdx.x, o = blockIdx.y;
  int t = threadIdx.x;
  if (t >= 32) return;
  float c0=gcons[o], c1=gcons[32+o], c2=gcons[64+o];
  float edt = F[(b*32+t)*16640];
  float v[32]; float mx=-1e30f;
  #pragma unroll
  for (int s=0;s<32;++s){
    float sc = c0*edt + c1*F[(b*32+s)*16640] + c2;
    for (int p=0;p<8;++p) sc += scoreP[(((p*2+b)*32+o)*32 + t)*32 + s];
    v[s]=sc; mx=fmaxf(mx,sc);
  }
  float sum=0.f;
  #pragma unroll
  for (int s=0;s<32;++s){ float e=expf(v[s]-mx); v[s]=e; sum+=e; }
  float inv=1.f/sum;
  float* row = attn + (b*32+o)*1024 + t*32;
  #pragma unroll
  for (int s=0;s<32;++s) row[s]=v[s]*inv;
}

__device__ __forceinline__ cf wcV_col0(const float* wV, int o, int fr){
  if (fr < 16)  return ldc(wV + ((o*16+fr)*16)*2);
  if (fr >= 112) return ldc(wV + (((32+o)*16+(fr-112))*16)*2);
  return make_float2(0.f,0.f);
}

// Pm[b,t,mh,kw] = sum_o d[o,m] * sum_s attn[b,o,t,s]*F[bs,m]
__global__ __launch_bounds__(256) void k_pmode(const float* __restrict__ F, const float* __restrict__ attn,
                        const float* __restrict__ wV, const float* __restrict__ wVs,
                        const float* __restrict__ wP, const float* __restrict__ wPs,
                        float* __restrict__ Pm){
  __shared__ float att[32][8][32];
  __shared__ cf Fsh[32][32];
  __shared__ cf dsh[32][32];
  int b = blockIdx.x, mh = blockIdx.y, tg = blockIdx.z;
  int fr = mh<32 ? mh : mh+64;
  int half = (mh>=32)?1:0, mr = mh&31;
  for (int i=threadIdx.x; i<8192; i+=256){
    int o = i>>8, r = i&255;
    att[o][r>>5][r&31] = attn[(b*32+o)*1024 + tg*256 + r];
  }
  for (int i=threadIdx.x; i<1024; i+=256){
    int s=i>>5, kw=i&31;
    Fsh[s][kw] = ldc(F + (((b*32+s)*128+fr)*65+kw)*2);
  }
  for (int i=threadIdx.x; i<1024; i+=256){
    int o=i>>5, kw=i&31;
    cf wp = ldc(wP + (((half*32+o)*32+mr)*32+kw)*2);
    cf bP = make_float2(wPs[o]+wp.x, wp.y);
    cf aV = make_float2(wVs[o], 0.f);
    if (kw==0){
      cf w1 = wcV_col0(wV,o,fr);
      cf w2 = wcV_col0(wV,o,(128-fr)&127);
      aV.x += 0.5f*(w1.x + w2.x);
      aV.y += 0.5f*(w1.y - w2.y);
    } else if (kw<16){
      if (fr<16){ cf wv=ldc(wV + ((o*16+fr)*16+kw)*2); aV.x+=wv.x; aV.y+=wv.y; }
      else if (fr>=112){ cf wv=ldc(wV + (((32+o)*16+(fr-112))*16+kw)*2); aV.x+=wv.x; aV.y+=wv.y; }
    }
    cf c = cmul(bP, aV);
    c.x -= wPs[o]*wVs[o];
    dsh[o][kw]=c;
  }
  __syncthreads();
  int tl = threadIdx.x>>5, kw = threadIdx.x&31;
  float ax=0.f, ay=0.f;
  for (int o=0;o<32;++o){
    float er=0.f, ei=0.f;
    #pragma unroll
    for (int s4=0;s4<32;s4+=4){
      float4 a4 = *(const float4*)&att[o][tl][s4];
      cf f0=Fsh[s4][kw], f1=Fsh[s4+1][kw], f2=Fsh[s4+2][kw], f3=Fsh[s4+3][kw];
      er=fmaf(a4.x,f0.x,er); ei=fmaf(a4.x,f0.y,ei);
      er=fmaf(a4.y,f1.x,er); ei=fmaf(a4.y,f1.y,ei);
      er=fmaf(a4.z,f2.x,er); ei=fmaf(a4.z,f2.y,ei);
      er=fmaf(a4.w,f3.x,er); ei=fmaf(a4.w,f3.y,ei);
    }
    cf d = dsh[o][kw];
    ax += d.x*er - d.y*ei;
    ay += d.x*ei + d.y*er;
  }
  int t = tg*8+tl;
  stc(Pm + ((b*32+t)*2048 + mh*32+kw)*2, make_float2(ax,ay));
}

// Projdhat[bt,m] = sum_s A[b,t,s]*F[bs,m] (+ Pm, + DC bias); A computed inline
__global__ __launch_bounds__(256) void k_pdhat(const float* __restrict__ F, const float* __restrict__ attn,
                        const float* __restrict__ wVs, const float* __restrict__ wPs,
                        const float* __restrict__ Pm,
                        const float* __restrict__ wP, const float* __restrict__ bPs,
                        const float* __restrict__ bVs, float* __restrict__ Pd){
  __shared__ float As[8][33];
  __shared__ float cvp[32];
  int b = blockIdx.x, tg = blockIdx.z;
  if (threadIdx.x < 32) cvp[threadIdx.x] = wVs[threadIdx.x]*wPs[threadIdx.x];
  __syncthreads();
  {
    int tl = threadIdx.x>>5, s = threadIdx.x&31;
    int t = tg*8+tl;
    float a=0.f;
    for (int o=0;o<32;++o) a = fmaf(attn[(b*32+o)*1024 + t*32 + s], cvp[o], a);
    As[tl][s] = a;
  }
  __syncthreads();
  int m = blockIdx.y*256 + threadIdx.x;
  if (m >= 8320) return;
  int kh = m/65, kw = m - kh*65;
  cf acc[8];
  #pragma unroll
  for (int j=0;j<8;++j) acc[j]=make_float2(0.f,0.f);
  for (int s=0;s<32;++s){
    cf Fv = ldc(F + ((b*32+s)*8320 + m)*2);
    #pragma unroll
    for (int j=0;j<8;++j){
      float a = As[j][s];
      acc[j].x = fmaf(a,Fv.x,acc[j].x);
      acc[j].y = fmaf(a,Fv.y,acc[j].y);
    }
  }
  bool inP = (kw<32) && (kh<32 || kh>=96);
  int mh = (kh<32)? kh : kh-64;
  cf dc = make_float2(0.f,0.f);
  if (m==0){
    dc.x = bPs[0];
    for (int o=0;o<32;++o){
      cf wp = ldc(wP + (o*1024)*2);
      dc.x += (wPs[o]+wp.x)*bVs[o];
      dc.y += wp.y*bVs[o];
    }
  }
  for (int j=0;j<8;++j){
    int t = tg*8+j;
    cf v = acc[j];
    if (inP){ cf p = ldc(Pm + ((b*32+t)*2048 + mh*32+kw)*2); v.x+=p.x; v.y+=p.y; }
    if (m==0){ v.x+=dc.x; v.y+=dc.y; }
    stc(Pd + ((b*32+t)*8320 + m)*2, v);
  }
}

// z = irfft-row(Ag) + x ; inorm stats via atomics (stats zeroed in k_gamma)
__global__ __launch_bounds__(256) void k_irfft_row_addx(const float* __restrict__ Ag, const float* __restrict__ x,
                                                        float* __restrict__ z, float* __restrict__ stats){
  __shared__ cf rowA[16][66];
  __shared__ cf tw[128];
  init_tw(tw,128,1.f);
  int n=blockIdx.x, h0=blockIdx.y*16;
  for (int i=threadIdx.x;i<1040;i+=256){
    int hl=i/65, kw=i-hl*65;
    rowA[hl][kw] = ldc(Ag + ((n*128+h0+hl)*65+kw)*2);
  }
  __syncthreads();
  float s=0.f,s2=0.f;
  for (int i=threadIdx.x;i<2048;i+=256){
    int hl=i>>7, w=i&127;
    float acc=0.f; int idx=0;
    for (int kw=0;kw<65;++kw){
      cf v=rowA[hl][kw]; cf t=tw[idx];
      float term=v.x*t.x - v.y*t.y;
      acc += (kw==0||kw==64)? term : 2.f*term;
      idx=(idx+w)&127;
    }
    int gi = n*16384 + (h0+hl)*128 + w;
    acc += x[gi];
    z[gi]=acc;
    s+=acc; s2=fmaf(acc,acc,s2);
  }
  breduce2(s,s2);
  if (threadIdx.x==0){ atomicAdd(&stats[n*2],s); atomicAdd(&stats[n*2+1],s2); }
}

// ---- fused per-image FNO layer kernels -----------------------------------
// SH layout: phase A: zb=[0,4096) floats, Tm=[4096,12288) (128x32 cf)
//            phase B: G =[0,4096) (64x32 cf)      (reads Tm)
//            phase C: Am=[4096,12288) (128x32 cf) (reads G, overwrites Tm)
//            phase D: reads Am

// layer 0: an = C1*z+Dc -> FNO(wM0) -> f0; m0 = gelu(inorm(f0)*g3+b3 + wM0s*an + bM0s)
__global__ __launch_bounds__(1024) void k_fno0(const float* __restrict__ z, const float* __restrict__ statsZ,
                        const float* __restrict__ ng, const float* __restrict__ nb,
                        const float* __restrict__ wM0, const float* __restrict__ wM0s,
                        const float* __restrict__ bM0s, float* __restrict__ m0out){
  __shared__ float SH[12288];
  __shared__ cf tw[128];
  init_tw(tw,128,-1.f);
  float* zb = SH;
  cf* Tm = (cf*)(SH+4096);
  cf* G  = (cf*)SH;
  cf* Am = (cf*)(SH+4096);
  int n = blockIdx.x;
  float Sz=statsZ[n*2], Sz2=statsZ[n*2+1];
  float mz=Sz*(1.f/16384.f), vz=Sz2*(1.f/16384.f)-mz*mz;
  float az=rsqrtf(vz+EPSV);
  float g1=ng[1], g2=ng[2];
  float vat=g1*g1*vz*az*az;
  float C1=az*g1*rsqrtf(vat+EPSV)*g2;
  float Dc=nb[2]-mz*C1;
  const float* zi = z + n*16384;
  // phase A: row DFT
  for (int q=0;q<4;++q){
    __syncthreads();
    for (int i=threadIdx.x;i<4096;i+=1024) zb[i] = fmaf(zi[q*4096+i], C1, Dc);
    __syncthreads();
    int hl = threadIdx.x>>5, kw = threadIdx.x&31;
    float re=0.f, im=0.f; int idx=0;
    for (int w=0;w<128;++w){
      float v=zb[hl*128+w]; cf t=tw[idx];
      re=fmaf(v,t.x,re); im=fmaf(v,t.y,im);
      idx=(idx+kw)&127;
    }
    Tm[(q*32+hl)*32+kw] = make_float2(re*(1.f/16384.f), im*(1.f/16384.f));
  }
  __syncthreads();
  // phase B: col DFT + weight
  {
    int kw = threadIdx.x&31;
    cf gout[2];
    for (int r=0;r<2;++r){
      int khi = (threadIdx.x>>5) + r*32;
      int khF = (khi<32)? khi : khi+64;
      float re=0.f, im=0.f; int idx=0;
      for (int h=0;h<128;++h){
        cf v=Tm[h*32+kw]; cf t=tw[idx];
        re += v.x*t.x - v.y*t.y; im += v.x*t.y + v.y*t.x;
        idx=(idx+khF)&127;
      }
      int half=(khi>=32)?1:0, mr=khi&31;
      cf wv = ldc(wM0 + ((half*32+mr)*32+kw)*2);
      gout[r] = cmul(make_float2(re,im), wv);
    }
    __syncthreads();   // all Tm reads done; G overwrites zb region (dead)
    for (int r=0;r<2;++r){
      int khi = (threadIdx.x>>5) + r*32;
      G[khi*32+kw] = gout[r];
    }
  }
  __syncthreads();
  // phase C: inverse col DFT (conj twiddles) -> Am (overwrites Tm)
  {
    int kw = threadIdx.x&31;
    for (int r=0;r<4;++r){
      int h = (threadIdx.x>>5) + r*32;
      float re=0.f, im=0.f;
      int idx=0;
      for (int khi=0;khi<32;++khi){
        cf v=G[khi*32+kw]; cf t=tw[idx];
        re += v.x*t.x + v.y*t.y; im += v.y*t.x - v.x*t.y;
        idx=(idx+h)&127;
      }
      idx = (96*h)&127;
      for (int khi=32;khi<64;++khi){
        cf v=G[khi*32+kw]; cf t=tw[idx];
        re += v.x*t.x + v.y*t.y; im += v.y*t.x - v.x*t.y;
        idx=(idx+h)&127;
      }
      Am[h*32+kw] = make_float2(re,im);
    }
  }
  __syncthreads();
  // phase D: inverse row (real), stats, gelu-mix, write m0
  int w = threadIdx.x&127, hb = threadIdx.x>>7;
  float f0[16];
  float s=0.f, s2=0.f;
  for (int k=0;k<16;++k){
    int h = k*8 + hb;
    float acc=0.f; int idx=0;
    for (int kw=0;kw<32;++kw){
      cf v=Am[h*32+kw]; cf t=tw[idx];
      float term = v.x*t.x + v.y*t.y;
      acc += kw? 2.f*term : term;
      idx=(idx+w)&127;
    }
    f0[k]=acc; s+=acc; s2=fmaf(acc,acc,s2);
  }
  breduce2(s,s2);
  float m0m=s*(1.f/16384.f), v0=s2*(1.f/16384.f)-m0m*m0m;
  float A0=rsqrtf(v0+EPSV)*ng[3];
  float B0=nb[3]-m0m*A0;
  float ws_=wM0s[0], bs_=bM0s[0];
  for (int k=0;k<16;++k){
    int h = k*8 + hb;
    int gi = n*16384 + h*128 + w;
    float an = fmaf(zi[h*128+w], C1, Dc);
    float pre = fmaf(f0[k],A0,B0) + fmaf(ws_,an,bs_);
    m0out[gi] = 0.5f*pre*(1.f+erff(pre*0.70710678118654752f));
  }
}

// layer 1: FNO(m0, wM1) -> f1; m1 = inorm(f1)*g4+b4 + wM1s*m0 + bM1s;
// out = inorm(m1)*g5+b5 + (z-mz)*az*g1+b1
__global__ __launch_bounds__(1024) void k_fno1(const float* __restrict__ m0, const float* __restrict__ z,
                        const float* __restrict__ statsZ,
                        const float* __restrict__ ng, const float* __restrict__ nb,
                        const float* __restrict__ wM1, const float* __restrict__ wM1s,
                        const float* __restrict__ bM1s, float* __restrict__ out){
  __shared__ float SH[12288];
  __shared__ cf tw[128];
  init_tw(tw,128,-1.f);
  float* zb = SH;
  cf* Tm = (cf*)(SH+4096);
  cf* G  = (cf*)SH;
  cf* Am = (cf*)(SH+4096);
  int n = blockIdx.x;
  const float* mi = m0 + n*16384;
  for (int q=0;q<4;++q){
    __syncthreads();
    for (int i=threadIdx.x;i<4096;i+=1024) zb[i] = mi[q*4096+i];
    __syncthreads();
    int hl = threadIdx.x>>5, kw = threadIdx.x&31;
    float re=0.f, im=0.f; int idx=0;
    for (int w=0;w<128;++w){
      float v=zb[hl*128+w]; cf t=tw[idx];
      re=fmaf(v,t.x,re); im=fmaf(v,t.y,im);
      idx=(idx+kw)&127;
    }
    Tm[(q*32+hl)*32+kw] = make_float2(re*(1.f/16384.f), im*(1.f/16384.f));
  }
  __syncthreads();
  {
    int kw = threadIdx.x&31;
    cf gout[2];
    for (int r=0;r<2;++r){
      int khi = (threadIdx.x>>5) + r*32;
      int khF = (khi<32)? khi : khi+64;
      float re=0.f, im=0.f; int idx=0;
      for (int h=0;h<128;++h){
        cf v=Tm[h*32+kw]; cf t=tw[idx];
        re += v.x*t.x - v.y*t.y; im += v.x*t.y + v.y*t.x;
        idx=(idx+khF)&127;
      }
      int half=(khi>=32)?1:0, mr=khi&31;
      cf wv = ldc(wM1 + ((half*32+mr)*32+kw)*2);
      gout[r] = cmul(make_float2(re,im), wv);
    }
    __syncthreads();
    for (int r=0;r<2;++r){
      int khi = (threadIdx.x>>5) + r*32;
      G[khi*32+kw] = gout[r];
    }
  }
  __syncthreads();
  {
    int kw = threadIdx.x&31;
    for (int r=0;r<4;++r){
      int h = (threadIdx.x>>5) + r*32;
      float re=0.f, im=0.f;
      int idx=0;
      for (int khi=0;khi<32;++khi){
        cf v=G[khi*32+kw]; cf t=tw[idx];
        re += v.x*t.x + v.y*t.y; im += v.y*t.x - v.x*t.y;
        idx=(idx+h)&127;
      }
      idx = (96*h)&127;
      for (int khi=32;khi<64;++khi){
        cf v=G[khi*32+kw]; cf t=tw[idx];
        re += v.x*t.x + v.y*t.y; im += v.y*t.x - v.x*t.y;
        idx=(idx+h)&127;
      }
      Am[h*32+kw] = make_float2(re,im);
    }
  }
  __syncthreads();
  int w = threadIdx.x&127, hb = threadIdx.x>>7;
  float f1[16];
  float s=0.f, s2=0.f;
  for (int k=0;k<16;++k){
    int h = k*8 + hb;
    float acc=0.f; int idx=0;
    for (int kw=0;kw<32;++kw){
      cf v=Am[h*32+kw]; cf t=tw[idx];
      float term = v.x*t.x + v.y*t.y;
      acc += kw? 2.f*term : term;
      idx=(idx+w)&127;
    }
    f1[k]=acc; s+=acc; s2=fmaf(acc,acc,s2);
  }
  breduce2(s,s2);
  float m1m=s*(1.f/16384.f), v1=s2*(1.f/16384.f)-m1m*m1m;
  float A1=rsqrtf(v1+EPSV)*ng[4];
  float Bc1=nb[4]-m1m*A1;
  float ws_=wM1s[0], bs_=bM1s[0];
  float t1=0.f, t2=0.f;
  for (int k=0;k<16;++k){
    int h = k*8 + hb;
    float v = fmaf(f1[k],A1,Bc1) + fmaf(ws_, mi[h*128+w], bs_);
    f1[k]=v;
    t1+=v; t2=fmaf(v,v,t2);
  }
  breduce2(t1,t2);
  float mm=t1*(1.f/16384.f), vv=t2*(1.f/16384.f)-mm*mm;
  float A2=rsqrtf(vv+EPSV)*ng[5];
  float B2c=nb[5]-mm*A2;
  float Sz=statsZ[n*2], Sz2=statsZ[n*2+1];
  float mz=Sz*(1.f/16384.f), vz=Sz2*(1.f/16384.f)-mz*mz;
  float Az=rsqrtf(vz+EPSV)*ng[1];
  float Bz=nb[1]-mz*Az;
  const float* zi = z + n*16384;
  for (int k=0;k<16;++k){
    int h = k*8 + hb;
    out[n*16384 + h*128 + w] = fmaf(f1[k],A2,B2c) + fmaf(zi[h*128+w],Az,Bz);
  }
}

// ---------------------------------------------------------------------------
extern "C" void kernel_launch(void* const* d_in, const int* in_sizes, int n_in,
                              void* d_out, int out_size, void* d_ws, size_t ws_size,
                              hipStream_t stream){
  (void)in_sizes; (void)n_in; (void)out_size; (void)ws_size;
  const float* x   = (const float*)d_in[0];
  const float* wK  = (const float*)d_in[1];
  const float* wKs = (const float*)d_in[2];
  const float* bKs = (const float*)d_in[3];
  const float* wQ  = (const float*)d_in[4];
  const float* wQs = (const float*)d_in[5];
  const float* bQs = (const float*)d_in[6];
  const float* wV  = (const float*)d_in[7];
  const float* wVs = (const float*)d_in[8];
  const float* bVs = (const float*)d_in[9];
  const float* wP  = (const float*)d_in[10];
  const float* wPs = (const float*)d_in[11];
  const float* bPs = (const float*)d_in[12];
  const float* wM0 = (const float*)d_in[13];
  const float* wM0s= (const float*)d_in[14];
  const float* bM0s= (const float*)d_in[15];
  const float* wM1 = (const float*)d_in[16];
  const float* wM1s= (const float*)d_in[17];
  const float* bM1s= (const float*)d_in[18];
  const float* ng  = (const float*)d_in[19];
  const float* nb  = (const float*)d_in[20];
  float* out = (float*)d_out;
  float* ws  = (float*)d_ws;

  // workspace layout (floats)
  float* F      = ws;                     // 1,064,960
  float* scoreP = F + 1064960;            //   524,288
  float* attn   = scoreP + 524288;        //    65,536
  float* stats  = attn + 65536;           //       512 (zeroed by k_gamma)
  float* Pm     = stats + 512;            //   262,144
  float* gcons  = Pm + 262144;            //       128
  float* gam    = gcons + 128;            //   135,168
  float* CwPd   = gam + 135168;           // 1,064,960 (Cw then Pd)
  float* Ag     = CwPd + 1064960;         // 1,064,960
  float* z      = Ag + 1064960;           // 1,048,576
  float* m0b    = z + 1048576;            // 1,048,576
  float* statsZ = stats;

  k_gamma<<<32,256,0,stream>>>(wQ,wQs,bQs, wK,wKs,bKs, gam, gcons, stats);
  k_row0<<<64,1024,0,stream>>>(x, ng, nb, CwPd);
  k_fft_col_full<<<dim3(64,17),256,0,stream>>>(CwPd, F, -1.f);
  k_score<<<dim3(2,32,8),256,0,stream>>>(F, gam, scoreP);
  k_softmax<<<dim3(2,32),64,0,stream>>>(attn, F, gcons, scoreP);
  k_pmode<<<dim3(2,64,4),256,0,stream>>>(F, attn, wV, wVs, wP, wPs, Pm);
  k_pdhat<<<dim3(2,33,4),256,0,stream>>>(F, attn, wVs, wPs, Pm, wP, bPs, bVs, CwPd);
  k_fft_col_full<<<dim3(64,17),256,0,stream>>>(CwPd, Ag, 1.f);
  k_irfft_row_addx<<<dim3(64,8),256,0,stream>>>(Ag, x, z, statsZ);
  k_fno0<<<64,1024,0,stream>>>(z, statsZ, ng, nb, wM0, wM0s, bM0s, m0b);
  k_fno1<<<64,1024,0,stream>>>(m0b, z, statsZ, ng, nb, wM1, wM1s, bM1s, out);
}

// Round 5
// 386.857 us; speedup vs baseline: 1.1578x; 1.1578x over previous
//
#include <hip/hip_runtime.h>
#include <math.h>

// ---------------------------------------------------------------------------
// CODA block on MI355X, fp32. 17 dispatches, all heavy kernels >=256 blocks.
//  gamma(+stats zero), xstats, rowDFT(x), colDFT fwd, score, softmax,
//  pmode, pdhat+inv-colDFT fused, irowDFT+x, rowDFT(an), colpair(M0),
//  irow(stats0), m0row, colpair(M1), irow(stats1), m1mix, final
// ---------------------------------------------------------------------------

#define EPSV 1e-5f
#define PI2 6.283185307179586f

typedef float2 cf;

__device__ __forceinline__ cf cmul(cf a, cf b){ return make_float2(a.x*b.x - a.y*b.y, a.x*b.y + a.y*b.x); }
__device__ __forceinline__ cf ldc(const float* p){ return make_float2(p[0], p[1]); }
__device__ __forceinline__ void stc(float* p, cf v){ p[0]=v.x; p[1]=v.y; }

__device__ __forceinline__ void init_tw(cf* tw, int N, float dir){
  for (int j = threadIdx.x; j < N; j += blockDim.x){
    float s, c; sincosf(dir * PI2 * (float)j / (float)N, &s, &c);
    tw[j] = make_float2(c, s);
  }
}

__device__ void breduce2(float& a, float& b){
  __shared__ float sha[8], shb[8];
  for (int off = 32; off > 0; off >>= 1){
    a += __shfl_down(a, off, 64);
    b += __shfl_down(b, off, 64);
  }
  int w = threadIdx.x >> 6, lane = threadIdx.x & 63;
  int nw = (blockDim.x + 63) >> 6;
  if (lane == 0){ sha[w] = a; shb[w] = b; }
  __syncthreads();
  if (threadIdx.x == 0){
    for (int i = 1; i < nw; ++i){ a += sha[i]; b += shb[i]; }
    sha[0] = a; shb[0] = b;
  }
  __syncthreads();
  a = sha[0]; b = shb[0];
  __syncthreads();
}

// --------------------------------------------------------------------------
// per-image inorm coefficients A,Bc
__global__ __launch_bounds__(256) void k_xstats(const float* __restrict__ x, const float* __restrict__ ng,
                                                const float* __restrict__ nb, float* __restrict__ normAB){
  int n = blockIdx.x;
  const float* im = x + n*16384;
  float s=0.f, s2=0.f;
  for (int i=threadIdx.x;i<16384;i+=256){ float v=im[i]; s+=v; s2=fmaf(v,v,s2); }
  breduce2(s,s2);
  if (threadIdx.x==0){
    float m = s*(1.f/16384.f), var = s2*(1.f/16384.f)-m*m;
    float A = rsqrtf(var+EPSV)*ng[0];
    normAB[n*2]=A; normAB[n*2+1]=nb[0]-m*A;
  }
}

// row rfft of inorm(x) (kw 0..64), scaled 1/16384; grid (64,8)
__global__ __launch_bounds__(256) void k_rfft_row_x(const float* __restrict__ x, const float* __restrict__ normAB,
                                                    float* __restrict__ Cw){
  __shared__ float tile[16][128];
  __shared__ cf tw[128];
  init_tw(tw, 128, -1.f);
  int n = blockIdx.x, h0 = blockIdx.y*16;
  float A = normAB[n*2], Bc = normAB[n*2+1];
  for (int i=threadIdx.x;i<2048;i+=256) tile[i>>7][i&127] = fmaf(x[n*16384 + h0*128 + i], A, Bc);
  __syncthreads();
  int hl = threadIdx.x >> 4, kws = threadIdx.x & 15;
  for (int kw=kws; kw<65; kw+=16){
    float re=0.f, im=0.f; int idx=0;
    for (int w=0;w<128;++w){
      float v=tile[hl][w]; cf t=tw[idx];
      re=fmaf(v,t.x,re); im=fmaf(v,t.y,im);
      idx=(idx+kw)&127;
    }
    float* d = Cw + (((n*128)+(h0+hl))*65 + kw)*2;
    d[0]=re*(1.f/16384.f); d[1]=im*(1.f/16384.f);
  }
}

// full complex 128-point DFT along first axis, 65 cols, forward; grid (64,17)
__global__ __launch_bounds__(256) void k_fft_col_full(const float* __restrict__ src, float* __restrict__ dst){
  __shared__ cf col[4][128];
  __shared__ cf tw[128];
  init_tw(tw, 128, -1.f);
  int n = blockIdx.x, kwb = blockIdx.y*4;
  for (int i=threadIdx.x;i<512;i+=256){
    int kwl=i>>7, h=i&127; int kw=kwb+kwl;
    col[kwl][h] = (kw<65) ? ldc(src + ((n*128+h)*65+kw)*2) : make_float2(0.f,0.f);
  }
  __syncthreads();
  int a = threadIdx.x & 127, base = threadIdx.x >> 7;
  for (int kwl=base; kwl<4; kwl+=2){
    int kw = kwb+kwl; if (kw>=65) continue;
    float re=0.f, im=0.f; int idx=0;
    for (int h=0;h<128;++h){
      cf v=col[kwl][h]; cf t=tw[idx];
      re = fmaf(v.x,t.x,re); re = fmaf(-v.y,t.y,re);
      im = fmaf(v.x,t.y,im); im = fmaf(v.y,t.x,im);
      idx=(idx+a)&127;
    }
    float* d = dst + ((n*128+a)*65+kw)*2; d[0]=re; d[1]=im;
  }
}

// ---- spectral attention-score machinery ----------------------------------
__device__ __forceinline__ cf kq_mode(const float* w, int o, int kh, int kw){
  if (kw < 16){
    if (kh < 16)  return ldc(w + ((o*16+kh)*16+kw)*2);
    if (kh >= 48) return ldc(w + (((32+o)*16+(kh-48))*16+kw)*2);
  }
  return make_float2(0.f,0.f);
}

// gamma[o][m], m over 64x33 grid; also zeroes stats (block 0)
__global__ __launch_bounds__(256) void k_gamma(const float* __restrict__ wQ, const float* __restrict__ wQs,
                      const float* __restrict__ bQs,
                      const float* __restrict__ wK, const float* __restrict__ wKs,
                      const float* __restrict__ bKs,
                      float* __restrict__ gam, float* __restrict__ gcons, float* __restrict__ stats){
  int o = blockIdx.x;
  if (o==0){ for (int i=threadIdx.x;i<512;i+=256) stats[i]=0.f; }
  float sQ=wQs[o], sK=wKs[o];
  for (int m = threadIdx.x; m < 2112; m += 256){
    int kh = m/33, kw = m-kh*33;
    cf g;
    if (kw == 0){
      int mh = (64-kh)&63;
      cf qp = kq_mode(wQ,o,kh,0);  qp.x += sQ;
      cf qm = kq_mode(wQ,o,mh,0);  qm.x += sQ;
      cf qt = make_float2(0.5f*(qp.x+qm.x), 0.5f*(qp.y-qm.y));
      cf kp = kq_mode(wK,o,kh,0);  kp.x += sK;
      cf km = kq_mode(wK,o,mh,0);  km.x += sK;
      cf kt = make_float2(0.5f*(kp.x+km.x), 0.5f*(kp.y-km.y));
      g = make_float2(64.f*(qt.x*kt.x + qt.y*kt.y), 64.f*(qt.y*kt.x - qt.x*kt.y));
    } else if (kw == 32){
      g = make_float2(64.f*sQ*sK, 0.f);
    } else {
      cf q = kq_mode(wQ,o,kh,kw); q.x += sQ;
      cf k = kq_mode(wK,o,kh,kw); k.x += sK;
      g = make_float2(128.f*(q.x*k.x + q.y*k.y), 128.f*(q.y*k.x - q.x*k.y));
    }
    stc(gam + (o*2112+m)*2, g);
  }
  if (threadIdx.x == 0){
    float qt0 = sQ + kq_mode(wQ,0,0,0).x*0.f + kq_mode(wQ,o,0,0).x;
    float kt0 = sK + kq_mode(wK,o,0,0).x;
    gcons[o]    = 64.f*bKs[o]*qt0;
    gcons[32+o] = 64.f*bQs[o]*kt0;
    gcons[64+o] = 64.f*bQs[o]*bKs[o];
  }
}

// scoreP[mk][b,o,t,s] = partial sum over m-slice; reads F directly
__global__ __launch_bounds__(256) void k_score(const float* __restrict__ F, const float* __restrict__ gam,
                                               float* __restrict__ scoreP){
  __shared__ float2 Esh[88][33];
  __shared__ float2 gsh[88];
  int b = blockIdx.x, o = blockIdx.y, mk = blockIdx.z;
  int m0 = mk*264;
  int t = threadIdx.x >> 3, s4 = (threadIdx.x & 7) << 2;
  float acc0=0.f,acc1=0.f,acc2=0.f,acc3=0.f;
  for (int ck=0; ck<3; ++ck){
    int mc = m0 + ck*88;
    __syncthreads();
    for (int i = threadIdx.x; i < 88*32; i += 256){
      int tt = i/88, j = i - tt*88;
      int m = mc + j;
      int kh = m/33, kw = m - kh*33;
      int fr = kh<32 ? kh : kh+64;
      const float* Fb = F + (b*32+tt)*16640;
      float2 v;
      if (kw < 32) v = *(const float2*)(Fb + (fr*65+kw)*2);
      else {
        int mh = (64-kh)&63;
        int fr2 = mh<32 ? mh : mh+64;
        float2 a = *(const float2*)(Fb + (fr*65+32)*2);
        float2 c = *(const float2*)(Fb + (fr2*65+32)*2);
        v = make_float2(0.5f*(a.x+c.x), 0.5f*(a.y-c.y));
      }
      Esh[j][tt] = v;
    }
    for (int j = threadIdx.x; j < 88; j += 256)
      gsh[j] = *(const float2*)(gam + (o*2112 + mc + j)*2);
    __syncthreads();
    for (int j=0;j<88;++j){
      float2 g = gsh[j];
      float2 Et = Esh[j][t];
      float a  = g.x*Et.x - g.y*Et.y;
      float bb = g.x*Et.y + g.y*Et.x;
      float2 e0=Esh[j][s4], e1=Esh[j][s4+1], e2=Esh[j][s4+2], e3=Esh[j][s4+3];
      acc0 = fmaf(a,e0.x,fmaf(bb,e0.y,acc0));
      acc1 = fmaf(a,e1.x,fmaf(bb,e1.y,acc1));
      acc2 = fmaf(a,e2.x,fmaf(bb,e2.y,acc2));
      acc3 = fmaf(a,e3.x,fmaf(bb,e3.y,acc3));
    }
  }
  float* sp = scoreP + (((mk*2+b)*32+o)*32 + t)*32 + s4;
  sp[0]=acc0; sp[1]=acc1; sp[2]=acc2; sp[3]=acc3;
}

// sum 8 partials + DC-linear terms, softmax over s -> attn
__global__ __launch_bounds__(64) void k_softmax(float* __restrict__ attn, const float* __restrict__ F,
                                                const float* __restrict__ gcons, const float* __restrict__ scoreP){
  int b = blockIdx.x, o = blockIdx.y;
  int t = threadIdx.x;
  if (t >= 32) return;
  float c0=gcons[o], c1=gcons[32+o], c2=gcons[64+o];
  float edt = F[(b*32+t)*16640];
  float v[32]; float mx=-1e30f;
  #pragma unroll
  for (int s=0;s<32;++s){
    float sc = c0*edt + c1*F[(b*32+s)*16640] + c2;
    for (int p=0;p<8;++p) sc += scoreP[(((p*2+b)*32+o)*32 + t)*32 + s];
    v[s]=sc; mx=fmaxf(mx,sc);
  }
  float sum=0.f;
  #pragma unroll
  for (int s=0;s<32;++s){ float e=expf(v[s]-mx); v[s]=e; sum+=e; }
  float inv=1.f/sum;
  float* row = attn + (b*32+o)*1024 + t*32;
  #pragma unroll
  for (int s=0;s<32;++s) row[s]=v[s]*inv;
}

__device__ __forceinline__ cf wcV_col0(const float* wV, int o, int fr){
  if (fr < 16)  return ldc(wV + ((o*16+fr)*16)*2);
  if (fr >= 112) return ldc(wV + (((32+o)*16+(fr-112))*16)*2);
  return make_float2(0.f,0.f);
}

// Pm[b,t,mh,kw] = sum_o d[o,m] * sum_s attn[b,o,t,s]*F[bs,m]; grid (2,64,4)
__global__ __launch_bounds__(256) void k_pmode(const float* __restrict__ F, const float* __restrict__ attn,
                        const float* __restrict__ wV, const float* __restrict__ wVs,
                        const float* __restrict__ wP, const float* __restrict__ wPs,
                        float* __restrict__ Pm){
  __shared__ float att[32][8][32];
  __shared__ cf Fsh[32][32];
  __shared__ cf dsh[32][32];
  int b = blockIdx.x, mh = blockIdx.y, tg = blockIdx.z;
  int fr = mh<32 ? mh : mh+64;
  int half = (mh>=32)?1:0, mr = mh&31;
  for (int i=threadIdx.x; i<8192; i+=256){
    int o = i>>8, r = i&255;
    att[o][r>>5][r&31] = attn[(b*32+o)*1024 + tg*256 + r];
  }
  for (int i=threadIdx.x; i<1024; i+=256){
    int s=i>>5, kw=i&31;
    Fsh[s][kw] = ldc(F + (((b*32+s)*128+fr)*65+kw)*2);
  }
  for (int i=threadIdx.x; i<1024; i+=256){
    int o=i>>5, kw=i&31;
    cf wp = ldc(wP + (((half*32+o)*32+mr)*32+kw)*2);
    cf bP = make_float2(wPs[o]+wp.x, wp.y);
    cf aV = make_float2(wVs[o], 0.f);
    if (kw==0){
      cf w1 = wcV_col0(wV,o,fr);
      cf w2 = wcV_col0(wV,o,(128-fr)&127);
      aV.x += 0.5f*(w1.x + w2.x);
      aV.y += 0.5f*(w1.y - w2.y);
    } else if (kw<16){
      if (fr<16){ cf wv=ldc(wV + ((o*16+fr)*16+kw)*2); aV.x+=wv.x; aV.y+=wv.y; }
      else if (fr>=112){ cf wv=ldc(wV + (((32+o)*16+(fr-112))*16+kw)*2); aV.x+=wv.x; aV.y+=wv.y; }
    }
    cf c = cmul(bP, aV);
    c.x -= wPs[o]*wVs[o];
    dsh[o][kw]=c;
  }
  __syncthreads();
  int tl = threadIdx.x>>5, kw = threadIdx.x&31;
  float ax=0.f, ay=0.f;
  for (int o=0;o<32;++o){
    float er=0.f, ei=0.f;
    #pragma unroll
    for (int s4=0;s4<32;s4+=4){
      float4 a4 = *(const float4*)&att[o][tl][s4];
      cf f0=Fsh[s4][kw], f1=Fsh[s4+1][kw], f2=Fsh[s4+2][kw], f3=Fsh[s4+3][kw];
      er=fmaf(a4.x,f0.x,er); ei=fmaf(a4.x,f0.y,ei);
      er=fmaf(a4.y,f1.x,er); ei=fmaf(a4.y,f1.y,ei);
      er=fmaf(a4.z,f2.x,er); ei=fmaf(a4.z,f2.y,ei);
      er=fmaf(a4.w,f3.x,er); ei=fmaf(a4.w,f3.y,ei);
    }
    cf d = dsh[o][kw];
    ax += d.x*er - d.y*ei;
    ay += d.x*ei + d.y*er;
  }
  int t = tg*8+tl;
  stc(Pm + ((b*32+t)*2048 + mh*32+kw)*2, make_float2(ax,ay));
}

// fused: Projdhat (A-mix + Pm + DC) for one kw column + inverse col DFT -> Ag
// grid (2, 65, 4 tg); 256 thr
__global__ __launch_bounds__(256) void k_pdhat_icol(const float* __restrict__ F, const float* __restrict__ attn,
                        const float* __restrict__ wVs, const float* __restrict__ wPs,
                        const float* __restrict__ Pm,
                        const float* __restrict__ wP, const float* __restrict__ bPs,
                        const float* __restrict__ bVs, float* __restrict__ Ag){
  __shared__ cf Fsh[32][128];     // [s][kh]
  __shared__ cf Pdsh[128][9];     // [kh][t], padded
  __shared__ float As[8][33];
  __shared__ float cvp[32];
  __shared__ cf dcsh;
  __shared__ cf tw[128];
  init_tw(tw, 128, 1.f);
  int b = blockIdx.x, kw = blockIdx.y, tg = blockIdx.z;
  if (threadIdx.x < 32) cvp[threadIdx.x] = wVs[threadIdx.x]*wPs[threadIdx.x];
  if (kw==0 && threadIdx.x==64){
    cf dc = make_float2(bPs[0], 0.f);
    for (int o=0;o<32;++o){
      cf wp = ldc(wP + (o*1024)*2);
      dc.x += (wPs[o]+wp.x)*bVs[o];
      dc.y += wp.y*bVs[o];
    }
    dcsh = dc;
  }
  __syncthreads();
  {
    int tl = threadIdx.x>>5, s = threadIdx.x&31;
    int t = tg*8+tl;
    float a=0.f;
    for (int o=0;o<32;++o) a = fmaf(attn[(b*32+o)*1024 + t*32 + s], cvp[o], a);
    As[tl][s] = a;
  }
  for (int i=threadIdx.x; i<4096; i+=256){
    int s = i>>7, kh = i&127;
    Fsh[s][kh] = ldc(F + ((b*32+s)*8320 + kh*65 + kw)*2);
  }
  __syncthreads();
  // Projdhat for this kw column -> Pdsh
  {
    int kh = threadIdx.x & 127, tp = threadIdx.x >> 7;
    bool inP = (kw<32) && (kh<32 || kh>=96);
    int mh = (kh<32)? kh : kh-64;
    for (int j=0;j<4;++j){
      int tl = tp*4+j;
      float ax=0.f, ay=0.f;
      for (int s=0;s<32;++s){
        float a = As[tl][s]; cf Fv = Fsh[s][kh];
        ax = fmaf(a,Fv.x,ax); ay = fmaf(a,Fv.y,ay);
      }
      if (inP){
        cf p = ldc(Pm + ((b*32+tg*8+tl)*2048 + mh*32+kw)*2);
        ax+=p.x; ay+=p.y;
      }
      if (kw==0 && kh==0){ ax+=dcsh.x; ay+=dcsh.y; }
      Pdsh[kh][tl] = make_float2(ax,ay);
    }
  }
  __syncthreads();
  // inverse col DFT: Ag[a][t] = sum_kh tw[+a*kh] * Pdsh[kh][t]
  {
    int a = threadIdx.x & 127, tp = threadIdx.x >> 7;
    for (int j=0;j<4;++j){
      int tl = tp*4+j;
      float re=0.f, im=0.f; int idx=0;
      for (int kh=0;kh<128;++kh){
        cf v = Pdsh[kh][tl]; cf t = tw[idx];
        re += v.x*t.x - v.y*t.y; im += v.x*t.y + v.y*t.x;
        idx=(idx+a)&127;
      }
      stc(Ag + ((b*32+tg*8+tl)*8320 + a*65 + kw)*2, make_float2(re,im));
    }
  }
}

// z = irfft-row(Ag) + x ; inorm stats via atomics
__global__ __launch_bounds__(256) void k_irfft_row_addx(const float* __restrict__ Ag, const float* __restrict__ x,
                                                        float* __restrict__ z, float* __restrict__ stats){
  __shared__ cf rowA[16][66];
  __shared__ cf tw[128];
  init_tw(tw,128,1.f);
  int n=blockIdx.x, h0=blockIdx.y*16;
  for (int i=threadIdx.x;i<1040;i+=256){
    int hl=i/65, kw=i-hl*65;
    rowA[hl][kw] = ldc(Ag + ((n*128+h0+hl)*65+kw)*2);
  }
  __syncthreads();
  float s=0.f,s2=0.f;
  for (int i=threadIdx.x;i<2048;i+=256){
    int hl=i>>7, w=i&127;
    float acc=0.f; int idx=0;
    for (int kw=0;kw<65;++kw){
      cf v=rowA[hl][kw]; cf t=tw[idx];
      float term=v.x*t.x - v.y*t.y;
      acc += (kw==0||kw==64)? term : 2.f*term;
      idx=(idx+w)&127;
    }
    int gi = n*16384 + (h0+hl)*128 + w;
    acc += x[gi];
    z[gi]=acc;
    s+=acc; s2=fmaf(acc,acc,s2);
  }
  breduce2(s,s2);
  if (threadIdx.x==0){ atomicAdd(&stats[n*2],s); atomicAdd(&stats[n*2+1],s2); }
}

// an pointwise + row DFT -> Tm ; grid (64,8)
__global__ __launch_bounds__(256) void k_rfft_row_an(const float* __restrict__ z, const float* __restrict__ statsZ,
                              const float* __restrict__ ng, const float* __restrict__ nb,
                              float* __restrict__ Tm){
  __shared__ float tile[16][128];
  __shared__ cf tw[128];
  init_tw(tw,128,-1.f);
  int n=blockIdx.x, h0=blockIdx.y*16;
  float S=statsZ[n*2], S2=statsZ[n*2+1];
  float mz=S*(1.f/16384.f), vz=S2*(1.f/16384.f)-mz*mz;
  float az=rsqrtf(vz+EPSV);
  float g1=ng[1], g2=ng[2], b2v=nb[2];
  float vat = g1*g1*vz*az*az;
  float C1 = az*g1*rsqrtf(vat+EPSV)*g2;
  float Dc = b2v - mz*C1;
  for (int i=threadIdx.x;i<2048;i+=256)
    tile[i>>7][i&127] = fmaf(z[n*16384+h0*128+i], C1, Dc);
  __syncthreads();
  for (int i=threadIdx.x;i<512;i+=256){
    int hl=i>>5, kw=i&31;
    float re=0.f,im=0.f; int idx=0;
    for (int w=0;w<128;++w){
      float v=tile[hl][w]; cf t=tw[idx];
      re=fmaf(v,t.x,re); im=fmaf(v,t.y,im);
      idx=(idx+kw)&127;
    }
    float* d = Tm + ((n*128+h0+hl)*32+kw)*2;
    d[0]=re*(1.f/16384.f); d[1]=im*(1.f/16384.f);
  }
}

// fused fwd col DFT + spectral weight + inverse col DFT; grid (64,4), 8 kw/blk
__global__ __launch_bounds__(256) void k_colpair(const float* __restrict__ Tm, const float* __restrict__ wM,
                                                 float* __restrict__ Am){
  __shared__ cf Tsh[128][9];
  __shared__ cf Gsh[64][9];
  __shared__ cf tw[128];
  init_tw(tw,128,-1.f);
  int n = blockIdx.x, kw8 = blockIdx.y*8;
  for (int i=threadIdx.x;i<1024;i+=256){
    int h=i>>3, kwl=i&7;
    Tsh[h][kwl] = ldc(Tm + ((n*128+h)*32 + kw8+kwl)*2);
  }
  __syncthreads();
  {
    int kwl = threadIdx.x&7, base = threadIdx.x>>3;   // base 0..31
    for (int r=0;r<2;++r){
      int khi = r*32 + base;
      int khF = (khi<32)? khi : khi+64;
      float re=0.f, im=0.f; int idx=0;
      for (int h=0;h<128;++h){
        cf v=Tsh[h][kwl]; cf t=tw[idx];
        re += v.x*t.x - v.y*t.y; im += v.x*t.y + v.y*t.x;
        idx=(idx+khF)&127;
      }
      int half=(khi>=32)?1:0, mr=khi&31;
      cf wv = ldc(wM + ((half*32+mr)*32 + kw8+kwl)*2);
      Gsh[khi][kwl] = cmul(make_float2(re,im), wv);
    }
  }
  __syncthreads();
  {
    int kwl = threadIdx.x&7, base = threadIdx.x>>3;
    for (int r=0;r<4;++r){
      int h = r*32 + base;
      float re=0.f, im=0.f;
      int idx=0;
      for (int khi=0;khi<32;++khi){
        cf v=Gsh[khi][kwl]; cf t=tw[idx];
        re += v.x*t.x + v.y*t.y; im += v.y*t.x - v.x*t.y;
        idx=(idx+h)&127;
      }
      idx = (96*h)&127;
      for (int khi=32;khi<64;++khi){
        cf v=Gsh[khi][kwl]; cf t=tw[idx];
        re += v.x*t.x + v.y*t.y; im += v.y*t.x - v.x*t.y;
        idx=(idx+h)&127;
      }
      stc(Am + ((n*128+h)*32 + kw8+kwl)*2, make_float2(re,im));
    }
  }
}

// irfft row stage for 32-col mode spectra; writes spatial + stats
__global__ __launch_bounds__(256) void k_mirfft_row(const float* __restrict__ Am, float* __restrict__ out,
                                                    float* __restrict__ stats){
  __shared__ cf rowA[16][33];
  __shared__ cf tw[128];
  init_tw(tw,128,1.f);
  int n=blockIdx.x, h0=blockIdx.y*16;
  for (int i=threadIdx.x;i<512;i+=256){
    int hl=i>>5, kw=i&31;
    rowA[hl][kw] = ldc(Am + ((n*128+h0+hl)*32+kw)*2);
  }
  __syncthreads();
  float s=0.f,s2=0.f;
  for (int i=threadIdx.x;i<2048;i+=256){
    int hl=i>>7, w=i&127;
    float acc=0.f; int idx=0;
    for (int kw=0;kw<32;++kw){
      cf v=rowA[hl][kw]; cf t=tw[idx];
      float term=v.x*t.x-v.y*t.y;
      acc += kw? 2.f*term:term;
      idx=(idx+w)&127;
    }
    out[n*16384+(h0+hl)*128+w]=acc;
    s+=acc; s2=fmaf(acc,acc,s2);
  }
  breduce2(s,s2);
  if (threadIdx.x==0){ atomicAdd(&stats[n*2],s); atomicAdd(&stats[n*2+1],s2); }
}

// m0 = gelu(inorm(fno0)*g3+b3 + wM0s*an + bM0s); writes m0 and M1's rfft-row
__global__ __launch_bounds__(256) void k_m0_rfft_row(const float* __restrict__ fno, const float* __restrict__ z,
                              const float* __restrict__ stats0, const float* __restrict__ statsZ,
                              const float* __restrict__ ng, const float* __restrict__ nb,
                              const float* __restrict__ wM0s, const float* __restrict__ bM0s,
                              float* __restrict__ m0out, float* __restrict__ Tm){
  __shared__ float tile[16][128];
  __shared__ cf tw[128];
  init_tw(tw,128,-1.f);
  int n=blockIdx.x, h0=blockIdx.y*16;
  float S0=stats0[n*2], S02=stats0[n*2+1];
  float m0m=S0*(1.f/16384.f), v0=S02*(1.f/16384.f)-m0m*m0m;
  float A0=rsqrtf(v0+EPSV)*ng[3];
  float B0=nb[3]-m0m*A0;
  float Sz=statsZ[n*2], Sz2=statsZ[n*2+1];
  float mz=Sz*(1.f/16384.f), vz=Sz2*(1.f/16384.f)-mz*mz;
  float az=rsqrtf(vz+EPSV);
  float g1=ng[1], g2=ng[2];
  float vat=g1*g1*vz*az*az;
  float C1=az*g1*rsqrtf(vat+EPSV)*g2;
  float Dc=nb[2]-mz*C1;
  float ws_=wM0s[0], bs_=bM0s[0];
  for (int i=threadIdx.x;i<2048;i+=256){
    int gi = n*16384 + h0*128 + i;
    float nf = fmaf(fno[gi], A0, B0);
    float an = fmaf(z[gi], C1, Dc);
    float pre = nf + fmaf(ws_, an, bs_);
    float gv = 0.5f*pre*(1.f+erff(pre*0.70710678118654752f));
    tile[i>>7][i&127]=gv;
    m0out[gi]=gv;
  }
  __syncthreads();
  for (int i=threadIdx.x;i<512;i+=256){
    int hl=i>>5, kw=i&31;
    float re=0.f,im=0.f; int idx=0;
    for (int w=0;w<128;++w){
      float v=tile[hl][w]; cf t=tw[idx];
      re=fmaf(v,t.x,re); im=fmaf(v,t.y,im);
      idx=(idx+kw)&127;
    }
    float* d = Tm + ((n*128+h0+hl)*32+kw)*2;
    d[0]=re*(1.f/16384.f); d[1]=im*(1.f/16384.f);
  }
}

// m1 = inorm(fno1)*g4+b4 + wM1s*m0 + bM1s; stats2
__global__ __launch_bounds__(256) void k_m1_mix(const float* fno1, const float* __restrict__ m0,
                         const float* __restrict__ stats1, const float* __restrict__ ng, const float* __restrict__ nb,
                         const float* __restrict__ wM1s, const float* __restrict__ bM1s,
                         float* m1out, float* __restrict__ stats2){
  int n=blockIdx.x, h0=blockIdx.y*16;
  float S=stats1[n*2], S2v=stats1[n*2+1];
  float m1m=S*(1.f/16384.f), v1=S2v*(1.f/16384.f)-m1m*m1m;
  float A1=rsqrtf(v1+EPSV)*ng[4];
  float Bc1=nb[4]-m1m*A1;
  float ws_=wM1s[0], bs_=bM1s[0];
  float s=0.f,s2=0.f;
  for (int i=threadIdx.x;i<2048;i+=256){
    int gi=n*16384+h0*128+i;
    float v = fmaf(fno1[gi],A1,Bc1) + fmaf(ws_,m0[gi],bs_);
    m1out[gi]=v;
    s+=v; s2=fmaf(v,v,s2);
  }
  breduce2(s,s2);
  if (threadIdx.x==0){ atomicAdd(&stats2[n*2],s); atomicAdd(&stats2[n*2+1],s2); }
}

// out = inorm(m1)*g5+b5 + attention
__global__ __launch_bounds__(256) void k_final(const float* __restrict__ m1, const float* __restrict__ z,
                        const float* __restrict__ stats2, const float* __restrict__ statsZ,
                        const float* __restrict__ ng, const float* __restrict__ nb,
                        float* __restrict__ out){
  int n=blockIdx.x, h0=blockIdx.y*16;
  float S=stats2[n*2], S2v=stats2[n*2+1];
  float mm=S*(1.f/16384.f), vv=S2v*(1.f/16384.f)-mm*mm;
  float A2=rsqrtf(vv+EPSV)*ng[5];
  float B2c=nb[5]-mm*A2;
  float Sz=statsZ[n*2], Sz2=statsZ[n*2+1];
  float mz=Sz*(1.f/16384.f), vz=Sz2*(1.f/16384.f)-mz*mz;
  float Az=rsqrtf(vz+EPSV)*ng[1];
  float Bz=nb[1]-mz*Az;
  for (int i=threadIdx.x;i<2048;i+=256){
    int gi=n*16384+h0*128+i;
    out[gi] = fmaf(m1[gi],A2,B2c) + fmaf(z[gi],Az,Bz);
  }
}

// ---------------------------------------------------------------------------
extern "C" void kernel_launch(void* const* d_in, const int* in_sizes, int n_in,
                              void* d_out, int out_size, void* d_ws, size_t ws_size,
                              hipStream_t stream){
  (void)in_sizes; (void)n_in; (void)out_size; (void)ws_size;
  const float* x   = (const float*)d_in[0];
  const float* wK  = (const float*)d_in[1];
  const float* wKs = (const float*)d_in[2];
  const float* bKs = (const float*)d_in[3];
  const float* wQ  = (const float*)d_in[4];
  const float* wQs = (const float*)d_in[5];
  const float* bQs = (const float*)d_in[6];
  const float* wV  = (const float*)d_in[7];
  const float* wVs = (const float*)d_in[8];
  const float* bVs = (const float*)d_in[9];
  const float* wP  = (const float*)d_in[10];
  const float* wPs = (const float*)d_in[11];
  const float* bPs = (const float*)d_in[12];
  const float* wM0 = (const float*)d_in[13];
  const float* wM0s= (const float*)d_in[14];
  const float* bM0s= (const float*)d_in[15];
  const float* wM1 = (const float*)d_in[16];
  const float* wM1s= (const float*)d_in[17];
  const float* bM1s= (const float*)d_in[18];
  const float* ng  = (const float*)d_in[19];
  const float* nb  = (const float*)d_in[20];
  float* out = (float*)d_out;
  float* ws  = (float*)d_ws;

  // workspace layout (floats)
  float* F      = ws;                     // 1,064,960
  float* scoreP = F + 1064960;            //   524,288
  float* attn   = scoreP + 524288;        //    65,536
  float* stats  = attn + 65536;           //       512 (zeroed by k_gamma)
  float* Pm     = stats + 512;            //   262,144
  float* gcons  = Pm + 262144;            //       128
  float* gam    = gcons + 128;            //   135,168
  float* normAB = gam + 135168;           //       128
  float* Cw     = normAB + 128;           // 1,064,960
  float* Ag     = Cw + 1064960;           // 1,064,960
  float* z      = Ag + 1064960;           // 1,048,576
  float* m0b    = z + 1048576;            // 1,048,576
  float* fx     = m0b + 1048576;          // 1,048,576
  float* Tm     = fx + 1048576;           //   524,288
  float* Am     = Tm + 524288;            //   524,288
  float* statsZ = stats;
  float* stats0 = stats + 128;
  float* stats1 = stats + 256;
  float* stats2 = stats + 384;

  k_gamma<<<32,256,0,stream>>>(wQ,wQs,bQs, wK,wKs,bKs, gam, gcons, stats);
  k_xstats<<<64,256,0,stream>>>(x, ng, nb, normAB);
  k_rfft_row_x<<<dim3(64,8),256,0,stream>>>(x, normAB, Cw);
  k_fft_col_full<<<dim3(64,17),256,0,stream>>>(Cw, F);
  k_score<<<dim3(2,32,8),256,0,stream>>>(F, gam, scoreP);
  k_softmax<<<dim3(2,32),64,0,stream>>>(attn, F, gcons, scoreP);
  k_pmode<<<dim3(2,64,4),256,0,stream>>>(F, attn, wV, wVs, wP, wPs, Pm);
  k_pdhat_icol<<<dim3(2,65,4),256,0,stream>>>(F, attn, wVs, wPs, Pm, wP, bPs, bVs, Ag);
  k_irfft_row_addx<<<dim3(64,8),256,0,stream>>>(Ag, x, z, statsZ);
  k_rfft_row_an<<<dim3(64,8),256,0,stream>>>(z, statsZ, ng, nb, Tm);
  k_colpair<<<dim3(64,4),256,0,stream>>>(Tm, wM0, Am);
  k_mirfft_row<<<dim3(64,8),256,0,stream>>>(Am, fx, stats0);
  k_m0_rfft_row<<<dim3(64,8),256,0,stream>>>(fx, z, stats0, statsZ, ng, nb, wM0s, bM0s, m0b, Tm);
  k_colpair<<<dim3(64,4),256,0,stream>>>(Tm, wM1, Am);
  k_mirfft_row<<<dim3(64,8),256,0,stream>>>(Am, fx, stats1);
  k_m1_mix<<<dim3(64,8),256,0,stream>>>(fx, m0b, stats1, ng, nb, wM1s, bM1s, fx, stats2);
  k_final<<<dim3(64,8),256,0,stream>>>(fx, z, stats2, statsZ, ng, nb, out);
}

// Round 6
// 348.306 us; speedup vs baseline: 1.2859x; 1.1107x over previous
//
#include <hip/hip_runtime.h>
#include <math.h>

// ---------------------------------------------------------------------------
// CODA block on MI355X, fp32. 16 dispatches.
// Key structure: F only on truncated 64x33 mode grid; attention scores via
// Parseval in mode space; A-mix done SPATIALLY (irfft2(A-mix(F)) = A-mix(xa_n));
// only the P-mode-local part (Pm, 64x32 modes) is inverse-transformed.
// ---------------------------------------------------------------------------

#define EPSV 1e-5f
#define PI2 6.283185307179586f

typedef float2 cf;

__device__ __forceinline__ cf cmul(cf a, cf b){ return make_float2(a.x*b.x - a.y*b.y, a.x*b.y + a.y*b.x); }
__device__ __forceinline__ cf ldc(const float* p){ return make_float2(p[0], p[1]); }
__device__ __forceinline__ void stc(float* p, cf v){ p[0]=v.x; p[1]=v.y; }

__device__ __forceinline__ void init_tw(cf* tw, int N, float dir){
  for (int j = threadIdx.x; j < N; j += blockDim.x){
    float s, c; sincosf(dir * PI2 * (float)j / (float)N, &s, &c);
    tw[j] = make_float2(c, s);
  }
}

__device__ void breduce2(float& a, float& b){
  __shared__ float sha[8], shb[8];
  for (int off = 32; off > 0; off >>= 1){
    a += __shfl_down(a, off, 64);
    b += __shfl_down(b, off, 64);
  }
  int w = threadIdx.x >> 6, lane = threadIdx.x & 63;
  int nw = (blockDim.x + 63) >> 6;
  if (lane == 0){ sha[w] = a; shb[w] = b; }
  __syncthreads();
  if (threadIdx.x == 0){
    for (int i = 1; i < nw; ++i){ a += sha[i]; b += shb[i]; }
    sha[0] = a; shb[0] = b;
  }
  __syncthreads();
  a = sha[0]; b = shb[0];
  __syncthreads();
}

// --------------------------------------------------------------------------
// per-image inorm coefficients A,Bc
__global__ __launch_bounds__(256) void k_xstats(const float* __restrict__ x, const float* __restrict__ ng,
                                                const float* __restrict__ nb, float* __restrict__ normAB){
  int n = blockIdx.x;
  const float* im = x + n*16384;
  float s=0.f, s2=0.f;
  for (int i=threadIdx.x;i<16384;i+=256){ float v=im[i]; s+=v; s2=fmaf(v,v,s2); }
  breduce2(s,s2);
  if (threadIdx.x==0){
    float m = s*(1.f/16384.f), var = s2*(1.f/16384.f)-m*m;
    float A = rsqrtf(var+EPSV)*ng[0];
    normAB[n*2]=A; normAB[n*2+1]=nb[0]-m*A;
  }
}

// row rfft of inorm(x), kw 0..32 only, scaled 1/16384; grid (64,8)
__global__ __launch_bounds__(256) void k_rfft_row_x(const float* __restrict__ x, const float* __restrict__ normAB,
                                                    float* __restrict__ Cw){
  __shared__ float tile[16][128];
  __shared__ cf tw[128];
  init_tw(tw, 128, -1.f);
  int n = blockIdx.x, h0 = blockIdx.y*16;
  float A = normAB[n*2], Bc = normAB[n*2+1];
  for (int i=threadIdx.x;i<2048;i+=256) tile[i>>7][i&127] = fmaf(x[n*16384 + h0*128 + i], A, Bc);
  __syncthreads();
  int hl = threadIdx.x >> 4, kws = threadIdx.x & 15;
  for (int kw=kws; kw<33; kw+=16){
    float re=0.f, im=0.f; int idx=0;
    for (int w=0;w<128;++w){
      float v=tile[hl][w]; cf t=tw[idx];
      re=fmaf(v,t.x,re); im=fmaf(v,t.y,im);
      idx=(idx+kw)&127;
    }
    float* d = Cw + (((n*128)+(h0+hl))*33 + kw)*2;
    d[0]=re*(1.f/16384.f); d[1]=im*(1.f/16384.f);
  }
}

// truncated col DFT: F[n][r][kw], r<32 -> row r, r>=32 -> row r+64; kw 0..32
// grid (64, 9): 4 kw per block
__global__ __launch_bounds__(256) void k_fcol(const float* __restrict__ Cw, float* __restrict__ F){
  __shared__ cf col[4][128];
  __shared__ cf tw[128];
  init_tw(tw, 128, -1.f);
  int n = blockIdx.x, kwb = blockIdx.y*4;
  for (int i=threadIdx.x;i<512;i+=256){
    int kwl=i>>7, h=i&127; int kw=kwb+kwl;
    col[kwl][h] = (kw<33) ? ldc(Cw + ((n*128+h)*33+kw)*2) : make_float2(0.f,0.f);
  }
  __syncthreads();
  int r = threadIdx.x & 63, kwl = threadIdx.x >> 6;
  int kw = kwb + kwl;
  if (kw >= 33) return;
  int R = (r<32)? r : r+64;
  float re=0.f, im=0.f; int idx=0;
  for (int h=0;h<128;++h){
    cf v=col[kwl][h]; cf t=tw[idx];
    re = fmaf(v.x,t.x,re); re = fmaf(-v.y,t.y,re);
    im = fmaf(v.x,t.y,im); im = fmaf(v.y,t.x,im);
    idx=(idx+R)&127;
  }
  stc(F + ((n*64+r)*33+kw)*2, make_float2(re,im));
}

// ---- spectral attention-score machinery ----------------------------------
__device__ __forceinline__ cf kq_mode(const float* w, int o, int kh, int kw){
  if (kw < 16){
    if (kh < 16)  return ldc(w + ((o*16+kh)*16+kw)*2);
    if (kh >= 48) return ldc(w + (((32+o)*16+(kh-48))*16+kw)*2);
  }
  return make_float2(0.f,0.f);
}

// gamma[o][m], m over 64x33 grid; also zeroes stats (block 0)
__global__ __launch_bounds__(256) void k_gamma(const float* __restrict__ wQ, const float* __restrict__ wQs,
                      const float* __restrict__ bQs,
                      const float* __restrict__ wK, const float* __restrict__ wKs,
                      const float* __restrict__ bKs,
                      float* __restrict__ gam, float* __restrict__ gcons, float* __restrict__ stats){
  int o = blockIdx.x;
  if (o==0){ for (int i=threadIdx.x;i<512;i+=256) stats[i]=0.f; }
  float sQ=wQs[o], sK=wKs[o];
  for (int m = threadIdx.x; m < 2112; m += 256){
    int kh = m/33, kw = m-kh*33;
    cf g;
    if (kw == 0){
      int mh = (64-kh)&63;
      cf qp = kq_mode(wQ,o,kh,0);  qp.x += sQ;
      cf qm = kq_mode(wQ,o,mh,0);  qm.x += sQ;
      cf qt = make_float2(0.5f*(qp.x+qm.x), 0.5f*(qp.y-qm.y));
      cf kp = kq_mode(wK,o,kh,0);  kp.x += sK;
      cf km = kq_mode(wK,o,mh,0);  km.x += sK;
      cf kt = make_float2(0.5f*(kp.x+km.x), 0.5f*(kp.y-km.y));
      g = make_float2(64.f*(qt.x*kt.x + qt.y*kt.y), 64.f*(qt.y*kt.x - qt.x*kt.y));
    } else if (kw == 32){
      g = make_float2(64.f*sQ*sK, 0.f);
    } else {
      cf q = kq_mode(wQ,o,kh,kw); q.x += sQ;
      cf k = kq_mode(wK,o,kh,kw); k.x += sK;
      g = make_float2(128.f*(q.x*k.x + q.y*k.y), 128.f*(q.y*k.x - q.x*k.y));
    }
    stc(gam + (o*2112+m)*2, g);
  }
  if (threadIdx.x == 0){
    float qt0 = sQ + kq_mode(wQ,o,0,0).x;
    float kt0 = sK + kq_mode(wK,o,0,0).x;
    gcons[o]    = 64.f*bKs[o]*qt0;
    gcons[32+o] = 64.f*bQs[o]*kt0;
    gcons[64+o] = 64.f*bQs[o]*bKs[o];
  }
}

// scoreP[p][b,o,t,s] partials; grid (2,32,4), 256 thr = 128 tile-threads x 2 j-halves
// tile: 2 t x 4 s per thread
__global__ __launch_bounds__(256) void k_score(const float* __restrict__ F, const float* __restrict__ gam,
                                               float* __restrict__ scoreP){
  __shared__ float2 Esh[88][33];
  __shared__ float2 gsh[88];
  int b = blockIdx.x, o = blockIdx.y, mk = blockIdx.z;
  int m0 = mk*528;
  int tid127 = threadIdx.x & 127;
  int jhalf = threadIdx.x >> 7;
  int t0 = (tid127 >> 3) * 2;
  int s4 = (tid127 & 7) * 4;
  int jbase = jhalf * 44;
  float acc[2][4];
  #pragma unroll
  for (int i=0;i<2;++i) for (int k=0;k<4;++k) acc[i][k]=0.f;
  for (int ck=0; ck<6; ++ck){
    int mc = m0 + ck*88;
    __syncthreads();
    for (int i = threadIdx.x; i < 88*32; i += 256){
      int tt = i/88, j = i - tt*88;
      int m = mc + j;
      int kh = m/33, kw = m - kh*33;
      const float* Fb = F + (b*32+tt)*4224;
      float2 v;
      if (kw < 32) v = *(const float2*)(Fb + (kh*33+kw)*2);
      else {
        int mh = (64-kh)&63;
        float2 a = *(const float2*)(Fb + (kh*33+32)*2);
        float2 c = *(const float2*)(Fb + (mh*33+32)*2);
        v = make_float2(0.5f*(a.x+c.x), 0.5f*(a.y-c.y));
      }
      Esh[j][tt] = v;
    }
    for (int j = threadIdx.x; j < 88; j += 256)
      gsh[j] = *(const float2*)(gam + (o*2112 + mc + j)*2);
    __syncthreads();
    for (int jj=0;jj<44;++jj){
      int j = jbase + jj;
      float2 g = gsh[j];
      float2 Et0 = Esh[j][t0], Et1 = Esh[j][t0+1];
      float a0 = g.x*Et0.x - g.y*Et0.y;
      float b0 = g.x*Et0.y + g.y*Et0.x;
      float a1 = g.x*Et1.x - g.y*Et1.y;
      float b1 = g.x*Et1.y + g.y*Et1.x;
      #pragma unroll
      for (int k=0;k<4;++k){
        float2 e = Esh[j][s4+k];
        acc[0][k] = fmaf(a0,e.x,fmaf(b0,e.y,acc[0][k]));
        acc[1][k] = fmaf(a1,e.x,fmaf(b1,e.y,acc[1][k]));
      }
    }
  }
  int p = mk*2 + jhalf;
  #pragma unroll
  for (int i=0;i<2;++i){
    float* sp = scoreP + (((p*2+b)*32+o)*32 + (t0+i))*32 + s4;
    sp[0]=acc[i][0]; sp[1]=acc[i][1]; sp[2]=acc[i][2]; sp[3]=acc[i][3];
  }
}

// sum 8 partials + DC-linear terms, softmax over s -> attn
__global__ __launch_bounds__(64) void k_softmax(float* __restrict__ attn, const float* __restrict__ F,
                                                const float* __restrict__ gcons, const float* __restrict__ scoreP){
  int b = blockIdx.x, o = blockIdx.y;
  int t = threadIdx.x;
  if (t >= 32) return;
  float c0=gcons[o], c1=gcons[32+o], c2=gcons[64+o];
  float edt = F[(b*32+t)*4224];
  float v[32]; float mx=-1e30f;
  #pragma unroll
  for (int s=0;s<32;++s){
    float sc = c0*edt + c1*F[(b*32+s)*4224] + c2;
    for (int p=0;p<8;++p) sc += scoreP[(((p*2+b)*32+o)*32 + t)*32 + s];
    v[s]=sc; mx=fmaxf(mx,sc);
  }
  float sum=0.f;
  #pragma unroll
  for (int s=0;s<32;++s){ float e=expf(v[s]-mx); v[s]=e; sum+=e; }
  float inv=1.f/sum;
  float* row = attn + (b*32+o)*1024 + t*32;
  #pragma unroll
  for (int s=0;s<32;++s) row[s]=v[s]*inv;
}

__device__ __forceinline__ cf wcV_col0(const float* wV, int o, int fr){
  if (fr < 16)  return ldc(wV + ((o*16+fr)*16)*2);
  if (fr >= 112) return ldc(wV + (((32+o)*16+(fr-112))*16)*2);
  return make_float2(0.f,0.f);
}

// Pm[b,t,mh,kw] = sum_o d[o,m] * sum_s attn[b,o,t,s]*F[bs,m]; grid (2,64,4)
__global__ __launch_bounds__(256) void k_pmode(const float* __restrict__ F, const float* __restrict__ attn,
                        const float* __restrict__ wV, const float* __restrict__ wVs,
                        const float* __restrict__ wP, const float* __restrict__ wPs,
                        float* __restrict__ Pm){
  __shared__ float att[32][8][32];
  __shared__ cf Fsh[32][32];
  __shared__ cf dsh[32][32];
  int b = blockIdx.x, mh = blockIdx.y, tg = blockIdx.z;
  int fr = mh<32 ? mh : mh+64;
  int half = (mh>=32)?1:0, mr = mh&31;
  for (int i=threadIdx.x; i<8192; i+=256){
    int o = i>>8, r = i&255;
    att[o][r>>5][r&31] = attn[(b*32+o)*1024 + tg*256 + r];
  }
  for (int i=threadIdx.x; i<1024; i+=256){
    int s=i>>5, kw=i&31;
    Fsh[s][kw] = ldc(F + (((b*32+s)*64+mh)*33+kw)*2);
  }
  for (int i=threadIdx.x; i<1024; i+=256){
    int o=i>>5, kw=i&31;
    cf wp = ldc(wP + (((half*32+o)*32+mr)*32+kw)*2);
    cf bP = make_float2(wPs[o]+wp.x, wp.y);
    cf aV = make_float2(wVs[o], 0.f);
    if (kw==0){
      cf w1 = wcV_col0(wV,o,fr);
      cf w2 = wcV_col0(wV,o,(128-fr)&127);
      aV.x += 0.5f*(w1.x + w2.x);
      aV.y += 0.5f*(w1.y - w2.y);
    } else if (kw<16){
      if (fr<16){ cf wv=ldc(wV + ((o*16+fr)*16+kw)*2); aV.x+=wv.x; aV.y+=wv.y; }
      else if (fr>=112){ cf wv=ldc(wV + (((32+o)*16+(fr-112))*16+kw)*2); aV.x+=wv.x; aV.y+=wv.y; }
    }
    cf c = cmul(bP, aV);
    c.x -= wPs[o]*wVs[o];
    dsh[o][kw]=c;
  }
  __syncthreads();
  int tl = threadIdx.x>>5, kw = threadIdx.x&31;
  float ax=0.f, ay=0.f;
  for (int o=0;o<32;++o){
    float er=0.f, ei=0.f;
    #pragma unroll
    for (int s4=0;s4<32;s4+=4){
      float4 a4 = *(const float4*)&att[o][tl][s4];
      cf f0=Fsh[s4][kw], f1=Fsh[s4+1][kw], f2=Fsh[s4+2][kw], f3=Fsh[s4+3][kw];
      er=fmaf(a4.x,f0.x,er); ei=fmaf(a4.x,f0.y,ei);
      er=fmaf(a4.y,f1.x,er); ei=fmaf(a4.y,f1.y,ei);
      er=fmaf(a4.z,f2.x,er); ei=fmaf(a4.z,f2.y,ei);
      er=fmaf(a4.w,f3.x,er); ei=fmaf(a4.w,f3.y,ei);
    }
    cf d = dsh[o][kw];
    ax += d.x*er - d.y*ei;
    ay += d.x*ei + d.y*er;
  }
  int t = tg*8+tl;
  stc(Pm + ((b*32+t)*2048 + mh*32+kw)*2, make_float2(ax,ay));
}

// z = spatial A-mix of x (+residual, +consts) + irfft2(Pm) ; stats
// grid (64 n, 8 hb), 256 thr
__global__ __launch_bounds__(256) void k_zmix(const float* __restrict__ x, const float* __restrict__ Pm,
                        const float* __restrict__ attn, const float* __restrict__ normAB,
                        const float* __restrict__ wVs, const float* __restrict__ wPs,
                        const float* __restrict__ wP, const float* __restrict__ bPs,
                        const float* __restrict__ bVs,
                        float* __restrict__ z, float* __restrict__ stats){
  __shared__ cf Pmsh[64][33];
  __shared__ cf PmAsh[16][33];
  __shared__ float Mrow[32];
  __shared__ float cpart[33];
  __shared__ float consts;
  __shared__ cf tw[128];
  init_tw(tw, 128, 1.f);
  int n = blockIdx.x, b = n>>5, t = n&31, h0 = blockIdx.y*16;
  for (int i=threadIdx.x;i<2048;i+=256)
    Pmsh[i>>5][i&31] = ldc(Pm + (n*2048 + i)*2);
  if (threadIdx.x < 32){
    int s = threadIdx.x;
    float a=0.f;
    for (int o=0;o<32;++o) a = fmaf(attn[(b*32+o)*1024 + t*32 + s], wVs[o]*wPs[o], a);
    float AxS = normAB[(b*32+s)*2], BcS = normAB[(b*32+s)*2+1];
    Mrow[s] = fmaf(a, AxS, (s==t)?1.f:0.f);
    cpart[s] = a*BcS;
  } else if (threadIdx.x == 32){
    float dcx = bPs[0];
    for (int o=0;o<32;++o){
      cf wp = ldc(wP + (o*1024)*2);
      dcx += (wPs[o]+wp.x)*bVs[o];
    }
    cpart[32] = dcx;
  }
  __syncthreads();
  if (threadIdx.x == 0){
    float c=0.f;
    for (int i=0;i<33;++i) c += cpart[i];
    consts = c;
  }
  // icol of Pm for rows h0..h0+15 (64 kh-modes -> rows 0..31 & 96..127)
  for (int r=0;r<2;++r){
    int idx2 = threadIdx.x + r*256;
    int hl = idx2>>5, kw = idx2&31;
    int h = h0+hl;
    float re=0.f, im=0.f;
    int idx=0;
    for (int khi=0;khi<32;++khi){
      cf v=Pmsh[khi][kw]; cf tt=tw[idx];
      re += v.x*tt.x - v.y*tt.y; im += v.x*tt.y + v.y*tt.x;
      idx=(idx+h)&127;
    }
    idx = (96*h)&127;
    for (int khi=32;khi<64;++khi){
      cf v=Pmsh[khi][kw]; cf tt=tw[idx];
      re += v.x*tt.x - v.y*tt.y; im += v.x*tt.y + v.y*tt.x;
      idx=(idx+h)&127;
    }
    PmAsh[hl][kw] = make_float2(re,im);
  }
  __syncthreads();
  float cst = consts;
  float s1=0.f, s2=0.f;
  const float* xb = x + b*32*16384;
  for (int ii=threadIdx.x; ii<512; ii+=256){
    int hl = ii>>5, wg = ii&31, w0 = wg*4;
    float acc0=cst, acc1=cst, acc2=cst, acc3=cst;
    // irow of PmA (32 kw, weight kw?2:1), 4 pixels
    int i0=0, i1=0, i2=0, i3=0;
    for (int kw=0;kw<32;++kw){
      cf v = PmAsh[hl][kw];
      float wt = kw? 2.f : 1.f;
      cf t0=tw[i0], t1=tw[i1], t2=tw[i2], t3=tw[i3];
      acc0 += wt*(v.x*t0.x - v.y*t0.y);
      acc1 += wt*(v.x*t1.x - v.y*t1.y);
      acc2 += wt*(v.x*t2.x - v.y*t2.y);
      acc3 += wt*(v.x*t3.x - v.y*t3.y);
      i0=(i0+w0)&127; i1=(i1+w0+1)&127; i2=(i2+w0+2)&127; i3=(i3+w0+3)&127;
    }
    // spatial token mix
    int off = (h0+hl)*128 + w0;
    for (int s=0;s<32;++s){
      float4 xv = *(const float4*)(xb + s*16384 + off);
      float m = Mrow[s];
      acc0 = fmaf(m,xv.x,acc0); acc1 = fmaf(m,xv.y,acc1);
      acc2 = fmaf(m,xv.z,acc2); acc3 = fmaf(m,xv.w,acc3);
    }
    *(float4*)(z + n*16384 + off) = make_float4(acc0,acc1,acc2,acc3);
    s1 += acc0+acc1+acc2+acc3;
    s2 += acc0*acc0+acc1*acc1+acc2*acc2+acc3*acc3;
  }
  breduce2(s1,s2);
  if (threadIdx.x==0){ atomicAdd(&stats[n*2],s1); atomicAdd(&stats[n*2+1],s2); }
}

// an pointwise + row DFT -> Tm ; grid (64,8)
__global__ __launch_bounds__(256) void k_rfft_row_an(const float* __restrict__ z, const float* __restrict__ statsZ,
                              const float* __restrict__ ng, const float* __restrict__ nb,
                              float* __restrict__ Tm){
  __shared__ float tile[16][128];
  __shared__ cf tw[128];
  init_tw(tw,128,-1.f);
  int n=blockIdx.x, h0=blockIdx.y*16;
  float S=statsZ[n*2], S2=statsZ[n*2+1];
  float mz=S*(1.f/16384.f), vz=S2*(1.f/16384.f)-mz*mz;
  float az=rsqrtf(vz+EPSV);
  float g1=ng[1], g2=ng[2], b2v=nb[2];
  float vat = g1*g1*vz*az*az;
  float C1 = az*g1*rsqrtf(vat+EPSV)*g2;
  float Dc = b2v - mz*C1;
  for (int i=threadIdx.x;i<2048;i+=256)
    tile[i>>7][i&127] = fmaf(z[n*16384+h0*128+i], C1, Dc);
  __syncthreads();
  for (int i=threadIdx.x;i<512;i+=256){
    int hl=i>>5, kw=i&31;
    float re=0.f,im=0.f; int idx=0;
    for (int w=0;w<128;++w){
      float v=tile[hl][w]; cf t=tw[idx];
      re=fmaf(v,t.x,re); im=fmaf(v,t.y,im);
      idx=(idx+kw)&127;
    }
    float* d = Tm + ((n*128+h0+hl)*32+kw)*2;
    d[0]=re*(1.f/16384.f); d[1]=im*(1.f/16384.f);
  }
}

// fused fwd col DFT + spectral weight + inverse col DFT; grid (64,4), 8 kw/blk
__global__ __launch_bounds__(256) void k_colpair(const float* __restrict__ Tm, const float* __restrict__ wM,
                                                 float* __restrict__ Am){
  __shared__ cf Tsh[128][9];
  __shared__ cf Gsh[64][9];
  __shared__ cf tw[128];
  init_tw(tw,128,-1.f);
  int n = blockIdx.x, kw8 = blockIdx.y*8;
  for (int i=threadIdx.x;i<1024;i+=256){
    int h=i>>3, kwl=i&7;
    Tsh[h][kwl] = ldc(Tm + ((n*128+h)*32 + kw8+kwl)*2);
  }
  __syncthreads();
  {
    int kwl = threadIdx.x&7, base = threadIdx.x>>3;
    for (int r=0;r<2;++r){
      int khi = r*32 + base;
      int khF = (khi<32)? khi : khi+64;
      float re=0.f, im=0.f; int idx=0;
      for (int h=0;h<128;++h){
        cf v=Tsh[h][kwl]; cf t=tw[idx];
        re += v.x*t.x - v.y*t.y; im += v.x*t.y + v.y*t.x;
        idx=(idx+khF)&127;
      }
      int half=(khi>=32)?1:0, mr=khi&31;
      cf wv = ldc(wM + ((half*32+mr)*32 + kw8+kwl)*2);
      Gsh[khi][kwl] = cmul(make_float2(re,im), wv);
    }
  }
  __syncthreads();
  {
    int kwl = threadIdx.x&7, base = threadIdx.x>>3;
    for (int r=0;r<4;++r){
      int h = r*32 + base;
      float re=0.f, im=0.f;
      int idx=0;
      for (int khi=0;khi<32;++khi){
        cf v=Gsh[khi][kwl]; cf t=tw[idx];
        re += v.x*t.x + v.y*t.y; im += v.y*t.x - v.x*t.y;
        idx=(idx+h)&127;
      }
      idx = (96*h)&127;
      for (int khi=32;khi<64;++khi){
        cf v=Gsh[khi][kwl]; cf t=tw[idx];
        re += v.x*t.x + v.y*t.y; im += v.y*t.x - v.x*t.y;
        idx=(idx+h)&127;
      }
      stc(Am + ((n*128+h)*32 + kw8+kwl)*2, make_float2(re,im));
    }
  }
}

// irfft row stage for 32-col mode spectra; writes spatial + stats
__global__ __launch_bounds__(256) void k_mirfft_row(const float* __restrict__ Am, float* __restrict__ out,
                                                    float* __restrict__ stats){
  __shared__ cf rowA[16][33];
  __shared__ cf tw[128];
  init_tw(tw,128,1.f);
  int n=blockIdx.x, h0=blockIdx.y*16;
  for (int i=threadIdx.x;i<512;i+=256){
    int hl=i>>5, kw=i&31;
    rowA[hl][kw] = ldc(Am + ((n*128+h0+hl)*32+kw)*2);
  }
  __syncthreads();
  float s=0.f,s2=0.f;
  for (int i=threadIdx.x;i<2048;i+=256){
    int hl=i>>7, w=i&127;
    float acc=0.f; int idx=0;
    for (int kw=0;kw<32;++kw){
      cf v=rowA[hl][kw]; cf t=tw[idx];
      float term=v.x*t.x-v.y*t.y;
      acc += kw? 2.f*term:term;
      idx=(idx+w)&127;
    }
    out[n*16384+(h0+hl)*128+w]=acc;
    s+=acc; s2=fmaf(acc,acc,s2);
  }
  breduce2(s,s2);
  if (threadIdx.x==0){ atomicAdd(&stats[n*2],s); atomicAdd(&stats[n*2+1],s2); }
}

// m0 = gelu(inorm(fno0)*g3+b3 + wM0s*an + bM0s); writes m0 and M1's rfft-row
__global__ __launch_bounds__(256) void k_m0_rfft_row(const float* __restrict__ fno, const float* __restrict__ z,
                              const float* __restrict__ stats0, const float* __restrict__ statsZ,
                              const float* __restrict__ ng, const float* __restrict__ nb,
                              const float* __restrict__ wM0s, const float* __restrict__ bM0s,
                              float* __restrict__ m0out, float* __restrict__ Tm){
  __shared__ float tile[16][128];
  __shared__ cf tw[128];
  init_tw(tw,128,-1.f);
  int n=blockIdx.x, h0=blockIdx.y*16;
  float S0=stats0[n*2], S02=stats0[n*2+1];
  float m0m=S0*(1.f/16384.f), v0=S02*(1.f/16384.f)-m0m*m0m;
  float A0=rsqrtf(v0+EPSV)*ng[3];
  float B0=nb[3]-m0m*A0;
  float Sz=statsZ[n*2], Sz2=statsZ[n*2+1];
  float mz=Sz*(1.f/16384.f), vz=Sz2*(1.f/16384.f)-mz*mz;
  float az=rsqrtf(vz+EPSV);
  float g1=ng[1], g2=ng[2];
  float vat=g1*g1*vz*az*az;
  float C1=az*g1*rsqrtf(vat+EPSV)*g2;
  float Dc=nb[2]-mz*C1;
  float ws_=wM0s[0], bs_=bM0s[0];
  for (int i=threadIdx.x;i<2048;i+=256){
    int gi = n*16384 + h0*128 + i;
    float nf = fmaf(fno[gi], A0, B0);
    float an = fmaf(z[gi], C1, Dc);
    float pre = nf + fmaf(ws_, an, bs_);
    float gv = 0.5f*pre*(1.f+erff(pre*0.70710678118654752f));
    tile[i>>7][i&127]=gv;
    m0out[gi]=gv;
  }
  __syncthreads();
  for (int i=threadIdx.x;i<512;i+=256){
    int hl=i>>5, kw=i&31;
    float re=0.f,im=0.f; int idx=0;
    for (int w=0;w<128;++w){
      float v=tile[hl][w]; cf t=tw[idx];
      re=fmaf(v,t.x,re); im=fmaf(v,t.y,im);
      idx=(idx+kw)&127;
    }
    float* d = Tm + ((n*128+h0+hl)*32+kw)*2;
    d[0]=re*(1.f/16384.f); d[1]=im*(1.f/16384.f);
  }
}

// m1 = inorm(fno1)*g4+b4 + wM1s*m0 + bM1s; stats2
__global__ __launch_bounds__(256) void k_m1_mix(const float* fno1, const float* __restrict__ m0,
                         const float* __restrict__ stats1, const float* __restrict__ ng, const float* __restrict__ nb,
                         const float* __restrict__ wM1s, const float* __restrict__ bM1s,
                         float* m1out, float* __restrict__ stats2){
  int n=blockIdx.x, h0=blockIdx.y*16;
  float S=stats1[n*2], S2v=stats1[n*2+1];
  float m1m=S*(1.f/16384.f), v1=S2v*(1.f/16384.f)-m1m*m1m;
  float A1=rsqrtf(v1+EPSV)*ng[4];
  float Bc1=nb[4]-m1m*A1;
  float ws_=wM1s[0], bs_=bM1s[0];
  float s=0.f,s2=0.f;
  for (int i=threadIdx.x;i<2048;i+=256){
    int gi=n*16384+h0*128+i;
    float v = fmaf(fno1[gi],A1,Bc1) + fmaf(ws_,m0[gi],bs_);
    m1out[gi]=v;
    s+=v; s2=fmaf(v,v,s2);
  }
  breduce2(s,s2);
  if (threadIdx.x==0){ atomicAdd(&stats2[n*2],s); atomicAdd(&stats2[n*2+1],s2); }
}

// out = inorm(m1)*g5+b5 + attention
__global__ __launch_bounds__(256) void k_final(const float* __restrict__ m1, const float* __restrict__ z,
                        const float* __restrict__ stats2, const float* __restrict__ statsZ,
                        const float* __restrict__ ng, const float* __restrict__ nb,
                        float* __restrict__ out){
  int n=blockIdx.x, h0=blockIdx.y*16;
  float S=stats2[n*2], S2v=stats2[n*2+1];
  float mm=S*(1.f/16384.f), vv=S2v*(1.f/16384.f)-mm*mm;
  float A2=rsqrtf(vv+EPSV)*ng[5];
  float B2c=nb[5]-mm*A2;
  float Sz=statsZ[n*2], Sz2=statsZ[n*2+1];
  float mz=Sz*(1.f/16384.f), vz=Sz2*(1.f/16384.f)-mz*mz;
  float Az=rsqrtf(vz+EPSV)*ng[1];
  float Bz=nb[1]-mz*Az;
  for (int i=threadIdx.x;i<2048;i+=256){
    int gi=n*16384+h0*128+i;
    out[gi] = fmaf(m1[gi],A2,B2c) + fmaf(z[gi],Az,Bz);
  }
}

// ---------------------------------------------------------------------------
extern "C" void kernel_launch(void* const* d_in, const int* in_sizes, int n_in,
                              void* d_out, int out_size, void* d_ws, size_t ws_size,
                              hipStream_t stream){
  (void)in_sizes; (void)n_in; (void)out_size; (void)ws_size;
  const float* x   = (const float*)d_in[0];
  const float* wK  = (const float*)d_in[1];
  const float* wKs = (const float*)d_in[2];
  const float* bKs = (const float*)d_in[3];
  const float* wQ  = (const float*)d_in[4];
  const float* wQs = (const float*)d_in[5];
  const float* bQs = (const float*)d_in[6];
  const float* wV  = (const float*)d_in[7];
  const float* wVs = (const float*)d_in[8];
  const float* bVs = (const float*)d_in[9];
  const float* wP  = (const float*)d_in[10];
  const float* wPs = (const float*)d_in[11];
  const float* bPs = (const float*)d_in[12];
  const float* wM0 = (const float*)d_in[13];
  const float* wM0s= (const float*)d_in[14];
  const float* bM0s= (const float*)d_in[15];
  const float* wM1 = (const float*)d_in[16];
  const float* wM1s= (const float*)d_in[17];
  const float* bM1s= (const float*)d_in[18];
  const float* ng  = (const float*)d_in[19];
  const float* nb  = (const float*)d_in[20];
  float* out = (float*)d_out;
  float* ws  = (float*)d_ws;

  // workspace layout (floats)
  float* F      = ws;                     //   270,336  (64 x 64 x 33 cf)
  float* Cw     = F + 270336;             //   540,672  (64 x 128 x 33 cf)
  float* scoreP = Cw + 540672;            //   524,288
  float* attn   = scoreP + 524288;        //    65,536
  float* stats  = attn + 65536;           //       512 (zeroed by k_gamma)
  float* Pm     = stats + 512;            //   262,144
  float* gcons  = Pm + 262144;            //       128
  float* gam    = gcons + 128;            //   135,168
  float* normAB = gam + 135168;           //       128
  float* z      = normAB + 128;           // 1,048,576
  float* m0b    = z + 1048576;            // 1,048,576
  float* fx     = m0b + 1048576;          // 1,048,576
  float* Tm     = fx + 1048576;           //   524,288
  float* Am     = Tm + 524288;            //   524,288
  float* statsZ = stats;
  float* stats0 = stats + 128;
  float* stats1 = stats + 256;
  float* stats2 = stats + 384;

  k_gamma<<<32,256,0,stream>>>(wQ,wQs,bQs, wK,wKs,bKs, gam, gcons, stats);
  k_xstats<<<64,256,0,stream>>>(x, ng, nb, normAB);
  k_rfft_row_x<<<dim3(64,8),256,0,stream>>>(x, normAB, Cw);
  k_fcol<<<dim3(64,9),256,0,stream>>>(Cw, F);
  k_score<<<dim3(2,32,4),256,0,stream>>>(F, gam, scoreP);
  k_softmax<<<dim3(2,32),64,0,stream>>>(attn, F, gcons, scoreP);
  k_pmode<<<dim3(2,64,4),256,0,stream>>>(F, attn, wV, wVs, wP, wPs, Pm);
  k_zmix<<<dim3(64,8),256,0,stream>>>(x, Pm, attn, normAB, wVs, wPs, wP, bPs, bVs, z, statsZ);
  k_rfft_row_an<<<dim3(64,8),256,0,stream>>>(z, statsZ, ng, nb, Tm);
  k_colpair<<<dim3(64,4),256,0,stream>>>(Tm, wM0, Am);
  k_mirfft_row<<<dim3(64,8),256,0,stream>>>(Am, fx, stats0);
  k_m0_rfft_row<<<dim3(64,8),256,0,stream>>>(fx, z, stats0, statsZ, ng, nb, wM0s, bM0s, m0b, Tm);
  k_colpair<<<dim3(64,4),256,0,stream>>>(Tm, wM1, Am);
  k_mirfft_row<<<dim3(64,8),256,0,stream>>>(Am, fx, stats1);
  k_m1_mix<<<dim3(64,8),256,0,stream>>>(fx, m0b, stats1, ng, nb, wM1s, bM1s, fx, stats2);
  k_final<<<dim3(64,8),256,0,stream>>>(fx, z, stats2, statsZ, ng, nb, out);
}

// Round 7
// 312.543 us; speedup vs baseline: 1.4331x; 1.1144x over previous
//
#include <hip/hip_runtime.h>
#include <math.h>

// ---------------------------------------------------------------------------
// CODA block on MI355X, fp32. 16 dispatches.
// F only on truncated 64x33 mode grid; scores via Parseval in mode space
// (k_score: 4 heads/block, 512 blocks); A-mix done SPATIALLY; only Pm
// (64x32 modes) is inverse-transformed.
// ---------------------------------------------------------------------------

#define EPSV 1e-5f
#define PI2 6.283185307179586f

typedef float2 cf;

__device__ __forceinline__ cf cmul(cf a, cf b){ return make_float2(a.x*b.x - a.y*b.y, a.x*b.y + a.y*b.x); }
__device__ __forceinline__ cf ldc(const float* p){ return make_float2(p[0], p[1]); }
__device__ __forceinline__ void stc(float* p, cf v){ p[0]=v.x; p[1]=v.y; }

__device__ __forceinline__ void init_tw(cf* tw, int N, float dir){
  for (int j = threadIdx.x; j < N; j += blockDim.x){
    float s, c; sincosf(dir * PI2 * (float)j / (float)N, &s, &c);
    tw[j] = make_float2(c, s);
  }
}

__device__ void breduce2(float& a, float& b){
  __shared__ float sha[8], shb[8];
  for (int off = 32; off > 0; off >>= 1){
    a += __shfl_down(a, off, 64);
    b += __shfl_down(b, off, 64);
  }
  int w = threadIdx.x >> 6, lane = threadIdx.x & 63;
  int nw = (blockDim.x + 63) >> 6;
  if (lane == 0){ sha[w] = a; shb[w] = b; }
  __syncthreads();
  if (threadIdx.x == 0){
    for (int i = 1; i < nw; ++i){ a += sha[i]; b += shb[i]; }
    sha[0] = a; shb[0] = b;
  }
  __syncthreads();
  a = sha[0]; b = shb[0];
  __syncthreads();
}

// --------------------------------------------------------------------------
// per-image inorm coefficients A,Bc
__global__ __launch_bounds__(256) void k_xstats(const float* __restrict__ x, const float* __restrict__ ng,
                                                const float* __restrict__ nb, float* __restrict__ normAB){
  int n = blockIdx.x;
  const float* im = x + n*16384;
  float s=0.f, s2=0.f;
  for (int i=threadIdx.x;i<16384;i+=256){ float v=im[i]; s+=v; s2=fmaf(v,v,s2); }
  breduce2(s,s2);
  if (threadIdx.x==0){
    float m = s*(1.f/16384.f), var = s2*(1.f/16384.f)-m*m;
    float A = rsqrtf(var+EPSV)*ng[0];
    normAB[n*2]=A; normAB[n*2+1]=nb[0]-m*A;
  }
}

// row rfft of inorm(x), kw 0..32 only, scaled 1/16384; grid (64,8)
__global__ __launch_bounds__(256) void k_rfft_row_x(const float* __restrict__ x, const float* __restrict__ normAB,
                                                    float* __restrict__ Cw){
  __shared__ float tile[16][128];
  __shared__ cf tw[128];
  init_tw(tw, 128, -1.f);
  int n = blockIdx.x, h0 = blockIdx.y*16;
  float A = normAB[n*2], Bc = normAB[n*2+1];
  for (int i=threadIdx.x;i<2048;i+=256) tile[i>>7][i&127] = fmaf(x[n*16384 + h0*128 + i], A, Bc);
  __syncthreads();
  int hl = threadIdx.x >> 4, kws = threadIdx.x & 15;
  for (int kw=kws; kw<33; kw+=16){
    float re=0.f, im=0.f; int idx=0;
    for (int w=0;w<128;++w){
      float v=tile[hl][w]; cf t=tw[idx];
      re=fmaf(v,t.x,re); im=fmaf(v,t.y,im);
      idx=(idx+kw)&127;
    }
    float* d = Cw + (((n*128)+(h0+hl))*33 + kw)*2;
    d[0]=re*(1.f/16384.f); d[1]=im*(1.f/16384.f);
  }
}

// truncated col DFT: F[n][r][kw], r<32 -> row r, r>=32 -> row r+64; kw 0..32
__global__ __launch_bounds__(256) void k_fcol(const float* __restrict__ Cw, float* __restrict__ F){
  __shared__ cf col[4][128];
  __shared__ cf tw[128];
  init_tw(tw, 128, -1.f);
  int n = blockIdx.x, kwb = blockIdx.y*4;
  for (int i=threadIdx.x;i<512;i+=256){
    int kwl=i>>7, h=i&127; int kw=kwb+kwl;
    col[kwl][h] = (kw<33) ? ldc(Cw + ((n*128+h)*33+kw)*2) : make_float2(0.f,0.f);
  }
  __syncthreads();
  int r = threadIdx.x & 63, kwl = threadIdx.x >> 6;
  int kw = kwb + kwl;
  if (kw >= 33) return;
  int R = (r<32)? r : r+64;
  float re=0.f, im=0.f; int idx=0;
  for (int h=0;h<128;++h){
    cf v=col[kwl][h]; cf t=tw[idx];
    re = fmaf(v.x,t.x,re); re = fmaf(-v.y,t.y,re);
    im = fmaf(v.x,t.y,im); im = fmaf(v.y,t.x,im);
    idx=(idx+R)&127;
  }
  stc(F + ((n*64+r)*33+kw)*2, make_float2(re,im));
}

// ---- spectral attention-score machinery ----------------------------------
__device__ __forceinline__ cf kq_mode(const float* w, int o, int kh, int kw){
  if (kw < 16){
    if (kh < 16)  return ldc(w + ((o*16+kh)*16+kw)*2);
    if (kh >= 48) return ldc(w + (((32+o)*16+(kh-48))*16+kw)*2);
  }
  return make_float2(0.f,0.f);
}

// gamma[o][m], m over 64x33 grid; also zeroes stats (block 0)
__global__ __launch_bounds__(256) void k_gamma(const float* __restrict__ wQ, const float* __restrict__ wQs,
                      const float* __restrict__ bQs,
                      const float* __restrict__ wK, const float* __restrict__ wKs,
                      const float* __restrict__ bKs,
                      float* __restrict__ gam, float* __restrict__ gcons, float* __restrict__ stats){
  int o = blockIdx.x;
  if (o==0){ for (int i=threadIdx.x;i<512;i+=256) stats[i]=0.f; }
  float sQ=wQs[o], sK=wKs[o];
  for (int m = threadIdx.x; m < 2112; m += 256){
    int kh = m/33, kw = m-kh*33;
    cf g;
    if (kw == 0){
      int mh = (64-kh)&63;
      cf qp = kq_mode(wQ,o,kh,0);  qp.x += sQ;
      cf qm = kq_mode(wQ,o,mh,0);  qm.x += sQ;
      cf qt = make_float2(0.5f*(qp.x+qm.x), 0.5f*(qp.y-qm.y));
      cf kp = kq_mode(wK,o,kh,0);  kp.x += sK;
      cf km = kq_mode(wK,o,mh,0);  km.x += sK;
      cf kt = make_float2(0.5f*(kp.x+km.x), 0.5f*(kp.y-km.y));
      g = make_float2(64.f*(qt.x*kt.x + qt.y*kt.y), 64.f*(qt.y*kt.x - qt.x*kt.y));
    } else if (kw == 32){
      g = make_float2(64.f*sQ*sK, 0.f);
    } else {
      cf q = kq_mode(wQ,o,kh,kw); q.x += sQ;
      cf k = kq_mode(wK,o,kh,kw); k.x += sK;
      g = make_float2(128.f*(q.x*k.x + q.y*k.y), 128.f*(q.y*k.x - q.x*k.y));
    }
    stc(gam + (o*2112+m)*2, g);
  }
  if (threadIdx.x == 0){
    float qt0 = sQ + kq_mode(wQ,o,0,0).x;
    float kt0 = sK + kq_mode(wK,o,0,0).x;
    gcons[o]    = 64.f*bKs[o]*qt0;
    gcons[32+o] = 64.f*bQs[o]*kt0;
    gcons[64+o] = 64.f*bQs[o]*bKs[o];
  }
}

// scoreP[mk][b,o,t,s] partials; grid (32 mk, 2 b, 8 og) = 512 blocks.
// Each block: 4 heads share one 66-mode E tile. Thread = (t, s4); 16 accs.
__global__ __launch_bounds__(256) void k_score(const float* __restrict__ F, const float* __restrict__ gam,
                                               float* __restrict__ scoreP){
  __shared__ float2 Esh[66][33];
  __shared__ float2 gsh[4][66];
  int mk = blockIdx.x, b = blockIdx.y, og = blockIdx.z;
  int m0 = mk*66;
  int t = threadIdx.x >> 3, s4 = (threadIdx.x & 7) << 2;
  // load E tile (gather from F, Hermitian fold at kw==32)
  for (int i = threadIdx.x; i < 2112; i += 256){
    int tt = i/66, j = i - tt*66;
    int m = m0 + j;
    int kh = m/33, kw = m - kh*33;
    const float* Fb = F + (b*32+tt)*4224;
    float2 v;
    if (kw < 32) v = *(const float2*)(Fb + (kh*33+kw)*2);
    else {
      int mh = (64-kh)&63;
      float2 a = *(const float2*)(Fb + (kh*33+32)*2);
      float2 c = *(const float2*)(Fb + (mh*33+32)*2);
      v = make_float2(0.5f*(a.x+c.x), 0.5f*(a.y-c.y));
    }
    Esh[j][tt] = v;
  }
  for (int i = threadIdx.x; i < 264; i += 256){
    int ol = i/66, j = i - ol*66;
    gsh[ol][j] = *(const float2*)(gam + ((og*4+ol)*2112 + m0 + j)*2);
  }
  __syncthreads();
  float acc[4][4];
  #pragma unroll
  for (int a=0;a<4;++a) for (int k=0;k<4;++k) acc[a][k]=0.f;
  #pragma unroll 2
  for (int j=0;j<66;++j){
    float2 et = Esh[j][t];
    float2 e0 = Esh[j][s4+0];
    float2 e1 = Esh[j][s4+1];
    float2 e2 = Esh[j][s4+2];
    float2 e3 = Esh[j][s4+3];
    #pragma unroll
    for (int ol=0;ol<4;++ol){
      float2 g = gsh[ol][j];
      float a  = g.x*et.x - g.y*et.y;
      float bb = g.x*et.y + g.y*et.x;
      acc[ol][0] = fmaf(a,e0.x,fmaf(bb,e0.y,acc[ol][0]));
      acc[ol][1] = fmaf(a,e1.x,fmaf(bb,e1.y,acc[ol][1]));
      acc[ol][2] = fmaf(a,e2.x,fmaf(bb,e2.y,acc[ol][2]));
      acc[ol][3] = fmaf(a,e3.x,fmaf(bb,e3.y,acc[ol][3]));
    }
  }
  #pragma unroll
  for (int ol=0;ol<4;++ol){
    int o = og*4+ol;
    float* sp = scoreP + (((mk*2+b)*32+o)*32 + t)*32 + s4;
    sp[0]=acc[ol][0]; sp[1]=acc[ol][1]; sp[2]=acc[ol][2]; sp[3]=acc[ol][3];
  }
}

// sum 32 partials + DC-linear terms, softmax over s -> attn; grid (2,32), 1024 thr
__global__ __launch_bounds__(1024) void k_softmax(float* __restrict__ attn, const float* __restrict__ F,
                                                const float* __restrict__ gcons, const float* __restrict__ scoreP){
  __shared__ float Ssh[32][33];
  int b = blockIdx.x, o = blockIdx.y;
  int t = threadIdx.x >> 5, s = threadIdx.x & 31;
  float c0=gcons[o], c1=gcons[32+o], c2=gcons[64+o];
  float sc = c0*F[(b*32+t)*4224] + c1*F[(b*32+s)*4224] + c2;
  #pragma unroll 8
  for (int p=0;p<32;++p) sc += scoreP[(((p*2+b)*32+o)*32 + t)*32 + s];
  Ssh[t][s] = sc;
  __syncthreads();
  float mx = -1e30f;
  for (int ss=0;ss<32;++ss) mx = fmaxf(mx, Ssh[t][ss]);
  float e = expf(sc - mx);
  __syncthreads();
  Ssh[t][s] = e;
  __syncthreads();
  float sum = 0.f;
  for (int ss=0;ss<32;++ss) sum += Ssh[t][ss];
  attn[(b*32+o)*1024 + t*32 + s] = e/sum;
}

__device__ __forceinline__ cf wcV_col0(const float* wV, int o, int fr){
  if (fr < 16)  return ldc(wV + ((o*16+fr)*16)*2);
  if (fr >= 112) return ldc(wV + (((32+o)*16+(fr-112))*16)*2);
  return make_float2(0.f,0.f);
}

// Pm[b,t,mh,kw] = sum_o d[o,m] * sum_s attn[b,o,t,s]*F[bs,m]; grid (2,64,4)
__global__ __launch_bounds__(256) void k_pmode(const float* __restrict__ F, const float* __restrict__ attn,
                        const float* __restrict__ wV, const float* __restrict__ wVs,
                        const float* __restrict__ wP, const float* __restrict__ wPs,
                        float* __restrict__ Pm){
  __shared__ float att[32][8][32];
  __shared__ cf Fsh[32][32];
  __shared__ cf dsh[32][32];
  int b = blockIdx.x, mh = blockIdx.y, tg = blockIdx.z;
  int fr = mh<32 ? mh : mh+64;
  int half = (mh>=32)?1:0, mr = mh&31;
  for (int i=threadIdx.x; i<8192; i+=256){
    int o = i>>8, r = i&255;
    att[o][r>>5][r&31] = attn[(b*32+o)*1024 + tg*256 + r];
  }
  for (int i=threadIdx.x; i<1024; i+=256){
    int s=i>>5, kw=i&31;
    Fsh[s][kw] = ldc(F + (((b*32+s)*64+mh)*33+kw)*2);
  }
  for (int i=threadIdx.x; i<1024; i+=256){
    int o=i>>5, kw=i&31;
    cf wp = ldc(wP + (((half*32+o)*32+mr)*32+kw)*2);
    cf bP = make_float2(wPs[o]+wp.x, wp.y);
    cf aV = make_float2(wVs[o], 0.f);
    if (kw==0){
      cf w1 = wcV_col0(wV,o,fr);
      cf w2 = wcV_col0(wV,o,(128-fr)&127);
      aV.x += 0.5f*(w1.x + w2.x);
      aV.y += 0.5f*(w1.y - w2.y);
    } else if (kw<16){
      if (fr<16){ cf wv=ldc(wV + ((o*16+fr)*16+kw)*2); aV.x+=wv.x; aV.y+=wv.y; }
      else if (fr>=112){ cf wv=ldc(wV + (((32+o)*16+(fr-112))*16+kw)*2); aV.x+=wv.x; aV.y+=wv.y; }
    }
    cf c = cmul(bP, aV);
    c.x -= wPs[o]*wVs[o];
    dsh[o][kw]=c;
  }
  __syncthreads();
  int tl = threadIdx.x>>5, kw = threadIdx.x&31;
  float ax=0.f, ay=0.f;
  for (int o=0;o<32;++o){
    float er=0.f, ei=0.f;
    #pragma unroll
    for (int s4=0;s4<32;s4+=4){
      float4 a4 = *(const float4*)&att[o][tl][s4];
      cf f0=Fsh[s4][kw], f1=Fsh[s4+1][kw], f2=Fsh[s4+2][kw], f3=Fsh[s4+3][kw];
      er=fmaf(a4.x,f0.x,er); ei=fmaf(a4.x,f0.y,ei);
      er=fmaf(a4.y,f1.x,er); ei=fmaf(a4.y,f1.y,ei);
      er=fmaf(a4.z,f2.x,er); ei=fmaf(a4.z,f2.y,ei);
      er=fmaf(a4.w,f3.x,er); ei=fmaf(a4.w,f3.y,ei);
    }
    cf d = dsh[o][kw];
    ax += d.x*er - d.y*ei;
    ay += d.x*ei + d.y*er;
  }
  int t = tg*8+tl;
  stc(Pm + ((b*32+t)*2048 + mh*32+kw)*2, make_float2(ax,ay));
}

// z = spatial A-mix of x (+residual, +consts) + irfft2(Pm) ; stats
__global__ __launch_bounds__(256) void k_zmix(const float* __restrict__ x, const float* __restrict__ Pm,
                        const float* __restrict__ attn, const float* __restrict__ normAB,
                        const float* __restrict__ wVs, const float* __restrict__ wPs,
                        const float* __restrict__ wP, const float* __restrict__ bPs,
                        const float* __restrict__ bVs,
                        float* __restrict__ z, float* __restrict__ stats){
  __shared__ cf Pmsh[64][33];
  __shared__ cf PmAsh[16][33];
  __shared__ float Mrow[32];
  __shared__ float cpart[33];
  __shared__ float consts;
  __shared__ cf tw[128];
  init_tw(tw, 128, 1.f);
  int n = blockIdx.x, b = n>>5, t = n&31, h0 = blockIdx.y*16;
  for (int i=threadIdx.x;i<2048;i+=256)
    Pmsh[i>>5][i&31] = ldc(Pm + (n*2048 + i)*2);
  if (threadIdx.x < 32){
    int s = threadIdx.x;
    float a=0.f;
    for (int o=0;o<32;++o) a = fmaf(attn[(b*32+o)*1024 + t*32 + s], wVs[o]*wPs[o], a);
    float AxS = normAB[(b*32+s)*2], BcS = normAB[(b*32+s)*2+1];
    Mrow[s] = fmaf(a, AxS, (s==t)?1.f:0.f);
    cpart[s] = a*BcS;
  } else if (threadIdx.x == 32){
    float dcx = bPs[0];
    for (int o=0;o<32;++o){
      cf wp = ldc(wP + (o*1024)*2);
      dcx += (wPs[o]+wp.x)*bVs[o];
    }
    cpart[32] = dcx;
  }
  __syncthreads();
  if (threadIdx.x == 0){
    float c=0.f;
    for (int i=0;i<33;++i) c += cpart[i];
    consts = c;
  }
  for (int r=0;r<2;++r){
    int idx2 = threadIdx.x + r*256;
    int hl = idx2>>5, kw = idx2&31;
    int h = h0+hl;
    float re=0.f, im=0.f;
    int idx=0;
    for (int khi=0;khi<32;++khi){
      cf v=Pmsh[khi][kw]; cf tt=tw[idx];
      re += v.x*tt.x - v.y*tt.y; im += v.x*tt.y + v.y*tt.x;
      idx=(idx+h)&127;
    }
    idx = (96*h)&127;
    for (int khi=32;khi<64;++khi){
      cf v=Pmsh[khi][kw]; cf tt=tw[idx];
      re += v.x*tt.x - v.y*tt.y; im += v.x*tt.y + v.y*tt.x;
      idx=(idx+h)&127;
    }
    PmAsh[hl][kw] = make_float2(re,im);
  }
  __syncthreads();
  float cst = consts;
  float s1=0.f, s2=0.f;
  const float* xb = x + b*32*16384;
  for (int ii=threadIdx.x; ii<512; ii+=256){
    int hl = ii>>5, wg = ii&31, w0 = wg*4;
    float acc0=cst, acc1=cst, acc2=cst, acc3=cst;
    int i0=0, i1=0, i2=0, i3=0;
    for (int kw=0;kw<32;++kw){
      cf v = PmAsh[hl][kw];
      float wt = kw? 2.f : 1.f;
      cf t0=tw[i0], t1=tw[i1], t2=tw[i2], t3=tw[i3];
      acc0 += wt*(v.x*t0.x - v.y*t0.y);
      acc1 += wt*(v.x*t1.x - v.y*t1.y);
      acc2 += wt*(v.x*t2.x - v.y*t2.y);
      acc3 += wt*(v.x*t3.x - v.y*t3.y);
      i0=(i0+w0)&127; i1=(i1+w0+1)&127; i2=(i2+w0+2)&127; i3=(i3+w0+3)&127;
    }
    int off = (h0+hl)*128 + w0;
    for (int s=0;s<32;++s){
      float4 xv = *(const float4*)(xb + s*16384 + off);
      float m = Mrow[s];
      acc0 = fmaf(m,xv.x,acc0); acc1 = fmaf(m,xv.y,acc1);
      acc2 = fmaf(m,xv.z,acc2); acc3 = fmaf(m,xv.w,acc3);
    }
    *(float4*)(z + n*16384 + off) = make_float4(acc0,acc1,acc2,acc3);
    s1 += acc0+acc1+acc2+acc3;
    s2 += acc0*acc0+acc1*acc1+acc2*acc2+acc3*acc3;
  }
  breduce2(s1,s2);
  if (threadIdx.x==0){ atomicAdd(&stats[n*2],s1); atomicAdd(&stats[n*2+1],s2); }
}

// an pointwise + row DFT -> Tm ; grid (64,8)
__global__ __launch_bounds__(256) void k_rfft_row_an(const float* __restrict__ z, const float* __restrict__ statsZ,
                              const float* __restrict__ ng, const float* __restrict__ nb,
                              float* __restrict__ Tm){
  __shared__ float tile[16][128];
  __shared__ cf tw[128];
  init_tw(tw,128,-1.f);
  int n=blockIdx.x, h0=blockIdx.y*16;
  float S=statsZ[n*2], S2=statsZ[n*2+1];
  float mz=S*(1.f/16384.f), vz=S2*(1.f/16384.f)-mz*mz;
  float az=rsqrtf(vz+EPSV);
  float g1=ng[1], g2=ng[2], b2v=nb[2];
  float vat = g1*g1*vz*az*az;
  float C1 = az*g1*rsqrtf(vat+EPSV)*g2;
  float Dc = b2v - mz*C1;
  for (int i=threadIdx.x;i<2048;i+=256)
    tile[i>>7][i&127] = fmaf(z[n*16384+h0*128+i], C1, Dc);
  __syncthreads();
  for (int i=threadIdx.x;i<512;i+=256){
    int hl=i>>5, kw=i&31;
    float re=0.f,im=0.f; int idx=0;
    for (int w=0;w<128;++w){
      float v=tile[hl][w]; cf t=tw[idx];
      re=fmaf(v,t.x,re); im=fmaf(v,t.y,im);
      idx=(idx+kw)&127;
    }
    float* d = Tm + ((n*128+h0+hl)*32+kw)*2;
    d[0]=re*(1.f/16384.f); d[1]=im*(1.f/16384.f);
  }
}

// fused fwd col DFT + spectral weight + inverse col DFT; grid (64,4), 8 kw/blk
__global__ __launch_bounds__(256) void k_colpair(const float* __restrict__ Tm, const float* __restrict__ wM,
                                                 float* __restrict__ Am){
  __shared__ cf Tsh[128][9];
  __shared__ cf Gsh[64][9];
  __shared__ cf tw[128];
  init_tw(tw,128,-1.f);
  int n = blockIdx.x, kw8 = blockIdx.y*8;
  for (int i=threadIdx.x;i<1024;i+=256){
    int h=i>>3, kwl=i&7;
    Tsh[h][kwl] = ldc(Tm + ((n*128+h)*32 + kw8+kwl)*2);
  }
  __syncthreads();
  {
    int kwl = threadIdx.x&7, base = threadIdx.x>>3;
    for (int r=0;r<2;++r){
      int khi = r*32 + base;
      int khF = (khi<32)? khi : khi+64;
      float re=0.f, im=0.f; int idx=0;
      for (int h=0;h<128;++h){
        cf v=Tsh[h][kwl]; cf t=tw[idx];
        re += v.x*t.x - v.y*t.y; im += v.x*t.y + v.y*t.x;
        idx=(idx+khF)&127;
      }
      int half=(khi>=32)?1:0, mr=khi&31;
      cf wv = ldc(wM + ((half*32+mr)*32 + kw8+kwl)*2);
      Gsh[khi][kwl] = cmul(make_float2(re,im), wv);
    }
  }
  __syncthreads();
  {
    int kwl = threadIdx.x&7, base = threadIdx.x>>3;
    for (int r=0;r<4;++r){
      int h = r*32 + base;
      float re=0.f, im=0.f;
      int idx=0;
      for (int khi=0;khi<32;++khi){
        cf v=Gsh[khi][kwl]; cf t=tw[idx];
        re += v.x*t.x + v.y*t.y; im += v.y*t.x - v.x*t.y;
        idx=(idx+h)&127;
      }
      idx = (96*h)&127;
      for (int khi=32;khi<64;++khi){
        cf v=Gsh[khi][kwl]; cf t=tw[idx];
        re += v.x*t.x + v.y*t.y; im += v.y*t.x - v.x*t.y;
        idx=(idx+h)&127;
      }
      stc(Am + ((n*128+h)*32 + kw8+kwl)*2, make_float2(re,im));
    }
  }
}

// irfft row stage for 32-col mode spectra; writes spatial + stats
__global__ __launch_bounds__(256) void k_mirfft_row(const float* __restrict__ Am, float* __restrict__ out,
                                                    float* __restrict__ stats){
  __shared__ cf rowA[16][33];
  __shared__ cf tw[128];
  init_tw(tw,128,1.f);
  int n=blockIdx.x, h0=blockIdx.y*16;
  for (int i=threadIdx.x;i<512;i+=256){
    int hl=i>>5, kw=i&31;
    rowA[hl][kw] = ldc(Am + ((n*128+h0+hl)*32+kw)*2);
  }
  __syncthreads();
  float s=0.f,s2=0.f;
  for (int i=threadIdx.x;i<2048;i+=256){
    int hl=i>>7, w=i&127;
    float acc=0.f; int idx=0;
    for (int kw=0;kw<32;++kw){
      cf v=rowA[hl][kw]; cf t=tw[idx];
      float term=v.x*t.x-v.y*t.y;
      acc += kw? 2.f*term:term;
      idx=(idx+w)&127;
    }
    out[n*16384+(h0+hl)*128+w]=acc;
    s+=acc; s2=fmaf(acc,acc,s2);
  }
  breduce2(s,s2);
  if (threadIdx.x==0){ atomicAdd(&stats[n*2],s); atomicAdd(&stats[n*2+1],s2); }
}

// m0 = gelu(inorm(fno0)*g3+b3 + wM0s*an + bM0s); writes m0 and M1's rfft-row
__global__ __launch_bounds__(256) void k_m0_rfft_row(const float* __restrict__ fno, const float* __restrict__ z,
                              const float* __restrict__ stats0, const float* __restrict__ statsZ,
                              const float* __restrict__ ng, const float* __restrict__ nb,
                              const float* __restrict__ wM0s, const float* __restrict__ bM0s,
                              float* __restrict__ m0out, float* __restrict__ Tm){
  __shared__ float tile[16][128];
  __shared__ cf tw[128];
  init_tw(tw,128,-1.f);
  int n=blockIdx.x, h0=blockIdx.y*16;
  float S0=stats0[n*2], S02=stats0[n*2+1];
  float m0m=S0*(1.f/16384.f), v0=S02*(1.f/16384.f)-m0m*m0m;
  float A0=rsqrtf(v0+EPSV)*ng[3];
  float B0=nb[3]-m0m*A0;
  float Sz=statsZ[n*2], Sz2=statsZ[n*2+1];
  float mz=Sz*(1.f/16384.f), vz=Sz2*(1.f/16384.f)-mz*mz;
  float az=rsqrtf(vz+EPSV);
  float g1=ng[1], g2=ng[2];
  float vat=g1*g1*vz*az*az;
  float C1=az*g1*rsqrtf(vat+EPSV)*g2;
  float Dc=nb[2]-mz*C1;
  float ws_=wM0s[0], bs_=bM0s[0];
  for (int i=threadIdx.x;i<2048;i+=256){
    int gi = n*16384 + h0*128 + i;
    float nf = fmaf(fno[gi], A0, B0);
    float an = fmaf(z[gi], C1, Dc);
    float pre = nf + fmaf(ws_, an, bs_);
    float gv = 0.5f*pre*(1.f+erff(pre*0.70710678118654752f));
    tile[i>>7][i&127]=gv;
    m0out[gi]=gv;
  }
  __syncthreads();
  for (int i=threadIdx.x;i<512;i+=256){
    int hl=i>>5, kw=i&31;
    float re=0.f,im=0.f; int idx=0;
    for (int w=0;w<128;++w){
      float v=tile[hl][w]; cf t=tw[idx];
      re=fmaf(v,t.x,re); im=fmaf(v,t.y,im);
      idx=(idx+kw)&127;
    }
    float* d = Tm + ((n*128+h0+hl)*32+kw)*2;
    d[0]=re*(1.f/16384.f); d[1]=im*(1.f/16384.f);
  }
}

// m1 = inorm(fno1)*g4+b4 + wM1s*m0 + bM1s; stats2
__global__ __launch_bounds__(256) void k_m1_mix(const float* fno1, const float* __restrict__ m0,
                         const float* __restrict__ stats1, const float* __restrict__ ng, const float* __restrict__ nb,
                         const float* __restrict__ wM1s, const float* __restrict__ bM1s,
                         float* m1out, float* __restrict__ stats2){
  int n=blockIdx.x, h0=blockIdx.y*16;
  float S=stats1[n*2], S2v=stats1[n*2+1];
  float m1m=S*(1.f/16384.f), v1=S2v*(1.f/16384.f)-m1m*m1m;
  float A1=rsqrtf(v1+EPSV)*ng[4];
  float Bc1=nb[4]-m1m*A1;
  float ws_=wM1s[0], bs_=bM1s[0];
  float s=0.f,s2=0.f;
  for (int i=threadIdx.x;i<2048;i+=256){
    int gi=n*16384+h0*128+i;
    float v = fmaf(fno1[gi],A1,Bc1) + fmaf(ws_,m0[gi],bs_);
    m1out[gi]=v;
    s+=v; s2=fmaf(v,v,s2);
  }
  breduce2(s,s2);
  if (threadIdx.x==0){ atomicAdd(&stats2[n*2],s); atomicAdd(&stats2[n*2+1],s2); }
}

// out = inorm(m1)*g5+b5 + attention
__global__ __launch_bounds__(256) void k_final(const float* __restrict__ m1, const float* __restrict__ z,
                        const float* __restrict__ stats2, const float* __restrict__ statsZ,
                        const float* __restrict__ ng, const float* __restrict__ nb,
                        float* __restrict__ out){
  int n=blockIdx.x, h0=blockIdx.y*16;
  float S=stats2[n*2], S2v=stats2[n*2+1];
  float mm=S*(1.f/16384.f), vv=S2v*(1.f/16384.f)-mm*mm;
  float A2=rsqrtf(vv+EPSV)*ng[5];
  float B2c=nb[5]-mm*A2;
  float Sz=statsZ[n*2], Sz2=statsZ[n*2+1];
  float mz=Sz*(1.f/16384.f), vz=Sz2*(1.f/16384.f)-mz*mz;
  float Az=rsqrtf(vz+EPSV)*ng[1];
  float Bz=nb[1]-mz*Az;
  for (int i=threadIdx.x;i<2048;i+=256){
    int gi=n*16384+h0*128+i;
    out[gi] = fmaf(m1[gi],A2,B2c) + fmaf(z[gi],Az,Bz);
  }
}

// ---------------------------------------------------------------------------
extern "C" void kernel_launch(void* const* d_in, const int* in_sizes, int n_in,
                              void* d_out, int out_size, void* d_ws, size_t ws_size,
                              hipStream_t stream){
  (void)in_sizes; (void)n_in; (void)out_size; (void)ws_size;
  const float* x   = (const float*)d_in[0];
  const float* wK  = (const float*)d_in[1];
  const float* wKs = (const float*)d_in[2];
  const float* bKs = (const float*)d_in[3];
  const float* wQ  = (const float*)d_in[4];
  const float* wQs = (const float*)d_in[5];
  const float* bQs = (const float*)d_in[6];
  const float* wV  = (const float*)d_in[7];
  const float* wVs = (const float*)d_in[8];
  const float* bVs = (const float*)d_in[9];
  const float* wP  = (const float*)d_in[10];
  const float* wPs = (const float*)d_in[11];
  const float* bPs = (const float*)d_in[12];
  const float* wM0 = (const float*)d_in[13];
  const float* wM0s= (const float*)d_in[14];
  const float* bM0s= (const float*)d_in[15];
  const float* wM1 = (const float*)d_in[16];
  const float* wM1s= (const float*)d_in[17];
  const float* bM1s= (const float*)d_in[18];
  const float* ng  = (const float*)d_in[19];
  const float* nb  = (const float*)d_in[20];
  float* out = (float*)d_out;
  float* ws  = (float*)d_ws;

  // workspace layout (floats)
  float* F      = ws;                     //   270,336
  float* Cw     = F + 270336;             //   540,672
  float* scoreP = Cw + 540672;            // 2,097,152
  float* attn   = scoreP + 2097152;       //    65,536
  float* stats  = attn + 65536;           //       512 (zeroed by k_gamma)
  float* Pm     = stats + 512;            //   262,144
  float* gcons  = Pm + 262144;            //       128
  float* gam    = gcons + 128;            //   135,168
  float* normAB = gam + 135168;           //       128
  float* z      = normAB + 128;           // 1,048,576
  float* m0b    = z + 1048576;            // 1,048,576
  float* fx     = m0b + 1048576;          // 1,048,576
  float* Tm     = fx + 1048576;           //   524,288
  float* Am     = Tm + 524288;            //   524,288
  float* statsZ = stats;
  float* stats0 = stats + 128;
  float* stats1 = stats + 256;
  float* stats2 = stats + 384;

  k_gamma<<<32,256,0,stream>>>(wQ,wQs,bQs, wK,wKs,bKs, gam, gcons, stats);
  k_xstats<<<64,256,0,stream>>>(x, ng, nb, normAB);
  k_rfft_row_x<<<dim3(64,8),256,0,stream>>>(x, normAB, Cw);
  k_fcol<<<dim3(64,9),256,0,stream>>>(Cw, F);
  k_score<<<dim3(32,2,8),256,0,stream>>>(F, gam, scoreP);
  k_softmax<<<dim3(2,32),1024,0,stream>>>(attn, F, gcons, scoreP);
  k_pmode<<<dim3(2,64,4),256,0,stream>>>(F, attn, wV, wVs, wP, wPs, Pm);
  k_zmix<<<dim3(64,8),256,0,stream>>>(x, Pm, attn, normAB, wVs, wPs, wP, bPs, bVs, z, statsZ);
  k_rfft_row_an<<<dim3(64,8),256,0,stream>>>(z, statsZ, ng, nb, Tm);
  k_colpair<<<dim3(64,4),256,0,stream>>>(Tm, wM0, Am);
  k_mirfft_row<<<dim3(64,8),256,0,stream>>>(Am, fx, stats0);
  k_m0_rfft_row<<<dim3(64,8),256,0,stream>>>(fx, z, stats0, statsZ, ng, nb, wM0s, bM0s, m0b, Tm);
  k_colpair<<<dim3(64,4),256,0,stream>>>(Tm, wM1, Am);
  k_mirfft_row<<<dim3(64,8),256,0,stream>>>(Am, fx, stats1);
  k_m1_mix<<<dim3(64,8),256,0,stream>>>(fx, m0b, stats1, ng, nb, wM1s, bM1s, fx, stats2);
  k_final<<<dim3(64,8),256,0,stream>>>(fx, z, stats2, statsZ, ng, nb, out);
}

// Round 8
// 261.320 us; speedup vs baseline: 1.7140x; 1.1960x over previous
//
#include <hip/hip_runtime.h>
#include <math.h>

// ---------------------------------------------------------------------------
// CODA block on MI355X, fp32. 15 dispatches.
// F on truncated 64x33 mode grid; scores via Parseval in mode space;
// A-mix done SPATIALLY; only Pm inverse-transformed. All 128-pt DFT inner
// loops use one radix-2 butterfly (u/v pre-combine or Se/So output pairs).
// ---------------------------------------------------------------------------

#define EPSV 1e-5f
#define PI2 6.283185307179586f

typedef float2 cf;

__device__ __forceinline__ cf cmul(cf a, cf b){ return make_float2(a.x*b.x - a.y*b.y, a.x*b.y + a.y*b.x); }
__device__ __forceinline__ cf ldc(const float* p){ return make_float2(p[0], p[1]); }
__device__ __forceinline__ void stc(float* p, cf v){ p[0]=v.x; p[1]=v.y; }

__device__ __forceinline__ void init_tw(cf* tw, int N, float dir){
  for (int j = threadIdx.x; j < N; j += blockDim.x){
    float s, c; sincosf(dir * PI2 * (float)j / (float)N, &s, &c);
    tw[j] = make_float2(c, s);
  }
}

__device__ void breduce2(float& a, float& b){
  __shared__ float sha[8], shb[8];
  for (int off = 32; off > 0; off >>= 1){
    a += __shfl_down(a, off, 64);
    b += __shfl_down(b, off, 64);
  }
  int w = threadIdx.x >> 6, lane = threadIdx.x & 63;
  int nw = (blockDim.x + 63) >> 6;
  if (lane == 0){ sha[w] = a; shb[w] = b; }
  __syncthreads();
  if (threadIdx.x == 0){
    for (int i = 1; i < nw; ++i){ a += sha[i]; b += shb[i]; }
    sha[0] = a; shb[0] = b;
  }
  __syncthreads();
  a = sha[0]; b = shb[0];
  __syncthreads();
}

// ---- spectral attention helpers ------------------------------------------
__device__ __forceinline__ cf kq_mode(const float* w, int o, int kh, int kw){
  if (kw < 16){
    if (kh < 16)  return ldc(w + ((o*16+kh)*16+kw)*2);
    if (kh >= 48) return ldc(w + (((32+o)*16+(kh-48))*16+kw)*2);
  }
  return make_float2(0.f,0.f);
}

// fused: blocks 0..31 = gamma (per head), 32..95 = per-image inorm coeffs
__global__ __launch_bounds__(256) void k_gamma_xstats(
                      const float* __restrict__ wQ, const float* __restrict__ wQs,
                      const float* __restrict__ bQs,
                      const float* __restrict__ wK, const float* __restrict__ wKs,
                      const float* __restrict__ bKs,
                      const float* __restrict__ x, const float* __restrict__ ng,
                      const float* __restrict__ nb,
                      float* __restrict__ gam, float* __restrict__ gcons,
                      float* __restrict__ stats, float* __restrict__ normAB){
  if (blockIdx.x >= 32){
    int n = blockIdx.x - 32;
    const float* im = x + n*16384;
    float s=0.f, s2=0.f;
    for (int i=threadIdx.x;i<16384;i+=256){ float v=im[i]; s+=v; s2=fmaf(v,v,s2); }
    breduce2(s,s2);
    if (threadIdx.x==0){
      float m = s*(1.f/16384.f), var = s2*(1.f/16384.f)-m*m;
      float A = rsqrtf(var+EPSV)*ng[0];
      normAB[n*2]=A; normAB[n*2+1]=nb[0]-m*A;
    }
    return;
  }
  int o = blockIdx.x;
  if (o==0){ for (int i=threadIdx.x;i<512;i+=256) stats[i]=0.f; }
  float sQ=wQs[o], sK=wKs[o];
  for (int m = threadIdx.x; m < 2112; m += 256){
    int kh = m/33, kw = m-kh*33;
    cf g;
    if (kw == 0){
      int mh = (64-kh)&63;
      cf qp = kq_mode(wQ,o,kh,0);  qp.x += sQ;
      cf qm = kq_mode(wQ,o,mh,0);  qm.x += sQ;
      cf qt = make_float2(0.5f*(qp.x+qm.x), 0.5f*(qp.y-qm.y));
      cf kp = kq_mode(wK,o,kh,0);  kp.x += sK;
      cf km = kq_mode(wK,o,mh,0);  km.x += sK;
      cf kt = make_float2(0.5f*(kp.x+km.x), 0.5f*(kp.y-km.y));
      g = make_float2(64.f*(qt.x*kt.x + qt.y*kt.y), 64.f*(qt.y*kt.x - qt.x*kt.y));
    } else if (kw == 32){
      g = make_float2(64.f*sQ*sK, 0.f);
    } else {
      cf q = kq_mode(wQ,o,kh,kw); q.x += sQ;
      cf k = kq_mode(wK,o,kh,kw); k.x += sK;
      g = make_float2(128.f*(q.x*k.x + q.y*k.y), 128.f*(q.y*k.x - q.x*k.y));
    }
    stc(gam + (o*2112+m)*2, g);
  }
  if (threadIdx.x == 0){
    float qt0 = sQ + kq_mode(wQ,o,0,0).x;
    float kt0 = sK + kq_mode(wK,o,0,0).x;
    gcons[o]    = 64.f*bKs[o]*qt0;
    gcons[32+o] = 64.f*bQs[o]*kt0;
    gcons[64+o] = 64.f*bQs[o]*bKs[o];
  }
}

// row rfft of inorm(x), kw 0..32, scaled 1/16384; radix-2 on w; grid (64,8)
__global__ __launch_bounds__(256) void k_rfft_row_x(const float* __restrict__ x, const float* __restrict__ normAB,
                                                    float* __restrict__ Cw){
  __shared__ float tile[16][128];
  __shared__ cf tw[128];
  init_tw(tw, 128, -1.f);
  int n = blockIdx.x, h0 = blockIdx.y*16;
  float A = normAB[n*2], Bc = normAB[n*2+1];
  for (int i=threadIdx.x;i<2048;i+=256) tile[i>>7][i&127] = fmaf(x[n*16384 + h0*128 + i], A, Bc);
  __syncthreads();
  for (int i=threadIdx.x;i<1024;i+=256){
    int hl=i>>6, w=i&63;
    float a=tile[hl][w], b=tile[hl][w+64];
    tile[hl][w]=a+b; tile[hl][w+64]=a-b;
  }
  __syncthreads();
  int hl = threadIdx.x >> 4, kws = threadIdx.x & 15;
  for (int kw=kws; kw<33; kw+=16){
    int sel = (kw&1)? 64 : 0;
    float re=0.f, im=0.f; int idx=0;
    for (int w=0;w<64;++w){
      float v=tile[hl][sel+w]; cf t=tw[idx];
      re=fmaf(v,t.x,re); im=fmaf(v,t.y,im);
      idx=(idx+kw)&127;
    }
    float* d = Cw + (((n*128)+(h0+hl))*33 + kw)*2;
    d[0]=re*(1.f/16384.f); d[1]=im*(1.f/16384.f);
  }
}

// truncated col DFT with radix-2 on h: F[n][r][kw]; grid (64,9)
__global__ __launch_bounds__(256) void k_fcol(const float* __restrict__ Cw, float* __restrict__ F){
  __shared__ cf col[4][128];
  __shared__ cf tw[128];
  init_tw(tw, 128, -1.f);
  int n = blockIdx.x, kwb = blockIdx.y*4;
  for (int i=threadIdx.x;i<512;i+=256){
    int kwl=i>>7, h=i&127; int kw=kwb+kwl;
    col[kwl][h] = (kw<33) ? ldc(Cw + ((n*128+h)*33+kw)*2) : make_float2(0.f,0.f);
  }
  __syncthreads();
  {
    int i = threadIdx.x;           // 256 = 4 kwl x 64 h
    int kwl = i>>6, h = i&63;
    cf a = col[kwl][h], b = col[kwl][h+64];
    col[kwl][h]    = make_float2(a.x+b.x, a.y+b.y);
    col[kwl][h+64] = make_float2(a.x-b.x, a.y-b.y);
  }
  __syncthreads();
  int r = threadIdx.x & 63, kwl = threadIdx.x >> 6;
  int kw = kwb + kwl;
  if (kw >= 33) return;
  int R = (r<32)? r : r+64;
  int sel = (r&1)? 64 : 0;
  float re=0.f, im=0.f; int idx=0;
  for (int j=0;j<64;++j){
    cf v=col[kwl][sel+j]; cf t=tw[idx];
    re = fmaf(v.x,t.x,re); re = fmaf(-v.y,t.y,re);
    im = fmaf(v.x,t.y,im); im = fmaf(v.y,t.x,im);
    idx=(idx+R)&127;
  }
  stc(F + ((n*64+r)*33+kw)*2, make_float2(re,im));
}

// scoreP partials; grid (32 mk, 2 b, 8 og); 4 heads share one 66-mode E tile
__global__ __launch_bounds__(256) void k_score(const float* __restrict__ F, const float* __restrict__ gam,
                                               float* __restrict__ scoreP){
  __shared__ float2 Esh[66][33];
  __shared__ float2 gsh[4][66];
  int mk = blockIdx.x, b = blockIdx.y, og = blockIdx.z;
  int m0 = mk*66;
  int t = threadIdx.x >> 3, s4 = (threadIdx.x & 7) << 2;
  for (int i = threadIdx.x; i < 2112; i += 256){
    int tt = i/66, j = i - tt*66;
    int m = m0 + j;
    int kh = m/33, kw = m - kh*33;
    const float* Fb = F + (b*32+tt)*4224;
    float2 v;
    if (kw < 32) v = *(const float2*)(Fb + (kh*33+kw)*2);
    else {
      int mh = (64-kh)&63;
      float2 a = *(const float2*)(Fb + (kh*33+32)*2);
      float2 c = *(const float2*)(Fb + (mh*33+32)*2);
      v = make_float2(0.5f*(a.x+c.x), 0.5f*(a.y-c.y));
    }
    Esh[j][tt] = v;
  }
  for (int i = threadIdx.x; i < 264; i += 256){
    int ol = i/66, j = i - ol*66;
    gsh[ol][j] = *(const float2*)(gam + ((og*4+ol)*2112 + m0 + j)*2);
  }
  __syncthreads();
  float acc[4][4];
  #pragma unroll
  for (int a=0;a<4;++a) for (int k=0;k<4;++k) acc[a][k]=0.f;
  #pragma unroll 2
  for (int j=0;j<66;++j){
    float2 et = Esh[j][t];
    float2 e0 = Esh[j][s4+0];
    float2 e1 = Esh[j][s4+1];
    float2 e2 = Esh[j][s4+2];
    float2 e3 = Esh[j][s4+3];
    #pragma unroll
    for (int ol=0;ol<4;++ol){
      float2 g = gsh[ol][j];
      float a  = g.x*et.x - g.y*et.y;
      float bb = g.x*et.y + g.y*et.x;
      acc[ol][0] = fmaf(a,e0.x,fmaf(bb,e0.y,acc[ol][0]));
      acc[ol][1] = fmaf(a,e1.x,fmaf(bb,e1.y,acc[ol][1]));
      acc[ol][2] = fmaf(a,e2.x,fmaf(bb,e2.y,acc[ol][2]));
      acc[ol][3] = fmaf(a,e3.x,fmaf(bb,e3.y,acc[ol][3]));
    }
  }
  #pragma unroll
  for (int ol=0;ol<4;++ol){
    int o = og*4+ol;
    float* sp = scoreP + (((mk*2+b)*32+o)*32 + t)*32 + s4;
    sp[0]=acc[ol][0]; sp[1]=acc[ol][1]; sp[2]=acc[ol][2]; sp[3]=acc[ol][3];
  }
}

// sum 32 partials + DC-linear terms, softmax over s -> attn
__global__ __launch_bounds__(1024) void k_softmax(float* __restrict__ attn, const float* __restrict__ F,
                                                const float* __restrict__ gcons, const float* __restrict__ scoreP){
  __shared__ float Ssh[32][33];
  int b = blockIdx.x, o = blockIdx.y;
  int t = threadIdx.x >> 5, s = threadIdx.x & 31;
  float c0=gcons[o], c1=gcons[32+o], c2=gcons[64+o];
  float sc = c0*F[(b*32+t)*4224] + c1*F[(b*32+s)*4224] + c2;
  #pragma unroll 8
  for (int p=0;p<32;++p) sc += scoreP[(((p*2+b)*32+o)*32 + t)*32 + s];
  Ssh[t][s] = sc;
  __syncthreads();
  float mx = -1e30f;
  for (int ss=0;ss<32;++ss) mx = fmaxf(mx, Ssh[t][ss]);
  float e = expf(sc - mx);
  __syncthreads();
  Ssh[t][s] = e;
  __syncthreads();
  float sum = 0.f;
  for (int ss=0;ss<32;++ss) sum += Ssh[t][ss];
  attn[(b*32+o)*1024 + t*32 + s] = e/sum;
}

__device__ __forceinline__ cf wcV_col0(const float* wV, int o, int fr){
  if (fr < 16)  return ldc(wV + ((o*16+fr)*16)*2);
  if (fr >= 112) return ldc(wV + (((32+o)*16+(fr-112))*16)*2);
  return make_float2(0.f,0.f);
}

// Pm[b,t,mh,kw] = sum_o d[o,m] * sum_s attn[b,o,t,s]*F[bs,m]; grid (2,64,4)
__global__ __launch_bounds__(256) void k_pmode(const float* __restrict__ F, const float* __restrict__ attn,
                        const float* __restrict__ wV, const float* __restrict__ wVs,
                        const float* __restrict__ wP, const float* __restrict__ wPs,
                        float* __restrict__ Pm){
  __shared__ float att[32][8][32];
  __shared__ cf Fsh[32][32];
  __shared__ cf dsh[32][32];
  int b = blockIdx.x, mh = blockIdx.y, tg = blockIdx.z;
  int fr = mh<32 ? mh : mh+64;
  int half = (mh>=32)?1:0, mr = mh&31;
  for (int i=threadIdx.x; i<8192; i+=256){
    int o = i>>8, r = i&255;
    att[o][r>>5][r&31] = attn[(b*32+o)*1024 + tg*256 + r];
  }
  for (int i=threadIdx.x; i<1024; i+=256){
    int s=i>>5, kw=i&31;
    Fsh[s][kw] = ldc(F + (((b*32+s)*64+mh)*33+kw)*2);
  }
  for (int i=threadIdx.x; i<1024; i+=256){
    int o=i>>5, kw=i&31;
    cf wp = ldc(wP + (((half*32+o)*32+mr)*32+kw)*2);
    cf bP = make_float2(wPs[o]+wp.x, wp.y);
    cf aV = make_float2(wVs[o], 0.f);
    if (kw==0){
      cf w1 = wcV_col0(wV,o,fr);
      cf w2 = wcV_col0(wV,o,(128-fr)&127);
      aV.x += 0.5f*(w1.x + w2.x);
      aV.y += 0.5f*(w1.y - w2.y);
    } else if (kw<16){
      if (fr<16){ cf wv=ldc(wV + ((o*16+fr)*16+kw)*2); aV.x+=wv.x; aV.y+=wv.y; }
      else if (fr>=112){ cf wv=ldc(wV + (((32+o)*16+(fr-112))*16+kw)*2); aV.x+=wv.x; aV.y+=wv.y; }
    }
    cf c = cmul(bP, aV);
    c.x -= wPs[o]*wVs[o];
    dsh[o][kw]=c;
  }
  __syncthreads();
  int tl = threadIdx.x>>5, kw = threadIdx.x&31;
  float ax=0.f, ay=0.f;
  for (int o=0;o<32;++o){
    float er=0.f, ei=0.f;
    #pragma unroll
    for (int s4=0;s4<32;s4+=4){
      float4 a4 = *(const float4*)&att[o][tl][s4];
      cf f0=Fsh[s4][kw], f1=Fsh[s4+1][kw], f2=Fsh[s4+2][kw], f3=Fsh[s4+3][kw];
      er=fmaf(a4.x,f0.x,er); ei=fmaf(a4.x,f0.y,ei);
      er=fmaf(a4.y,f1.x,er); ei=fmaf(a4.y,f1.y,ei);
      er=fmaf(a4.z,f2.x,er); ei=fmaf(a4.z,f2.y,ei);
      er=fmaf(a4.w,f3.x,er); ei=fmaf(a4.w,f3.y,ei);
    }
    cf d = dsh[o][kw];
    ax += d.x*er - d.y*ei;
    ay += d.x*ei + d.y*er;
  }
  int t = tg*8+tl;
  stc(Pm + ((b*32+t)*2048 + mh*32+kw)*2, make_float2(ax,ay));
}

// z = spatial A-mix of x + irfft2(Pm) + consts; stats. grid (64, 8 hb)
// block handles global rows {hb..hb+7} U {hb+64..hb+71}; radix-2 everywhere.
__global__ __launch_bounds__(256) void k_zmix(const float* __restrict__ x, const float* __restrict__ Pm,
                        const float* __restrict__ attn, const float* __restrict__ normAB,
                        const float* __restrict__ wVs, const float* __restrict__ wPs,
                        const float* __restrict__ wP, const float* __restrict__ bPs,
                        const float* __restrict__ bVs,
                        float* __restrict__ z, float* __restrict__ stats){
  __shared__ cf Pmsh[64][33];
  __shared__ cf PmAsh[16][33];    // rows 0..7: h=hb+l ; rows 8..15: h=hb+l+64
  __shared__ float Mrow[32];
  __shared__ float cpart[33];
  __shared__ float consts;
  __shared__ cf tw[128];
  init_tw(tw, 128, 1.f);
  int n = blockIdx.x, b = n>>5, t = n&31, hb = blockIdx.y*8;
  for (int i=threadIdx.x;i<2048;i+=256)
    Pmsh[i>>5][i&31] = ldc(Pm + (n*2048 + i)*2);
  if (threadIdx.x < 32){
    int s = threadIdx.x;
    float a=0.f;
    for (int o=0;o<32;++o) a = fmaf(attn[(b*32+o)*1024 + t*32 + s], wVs[o]*wPs[o], a);
    float AxS = normAB[(b*32+s)*2], BcS = normAB[(b*32+s)*2+1];
    Mrow[s] = fmaf(a, AxS, (s==t)?1.f:0.f);
    cpart[s] = a*BcS;
  } else if (threadIdx.x == 32){
    float dcx = bPs[0];
    for (int o=0;o<32;++o){
      cf wp = ldc(wP + (o*1024)*2);
      dcx += (wPs[o]+wp.x)*bVs[o];
    }
    cpart[32] = dcx;
  }
  __syncthreads();
  if (threadIdx.x == 0){
    float c=0.f;
    for (int i=0;i<33;++i) c += cpart[i];
    consts = c;
  }
  // icol: Se over even khi, So over odd; output pair h / h+64
  {
    int bl = threadIdx.x>>5, kw = threadIdx.x&31;
    int h = hb + bl;
    float ser=0.f, sei=0.f, sor=0.f, soi=0.f;
    int s2h = (2*h)&127;
    int idx = 0;
    for (int khi=0;khi<32;khi+=2){
      cf v=Pmsh[khi][kw]; cf tt=tw[idx];
      ser += v.x*tt.x - v.y*tt.y; sei += v.x*tt.y + v.y*tt.x;
      idx=(idx+s2h)&127;
    }
    idx = (96*h)&127;
    for (int khi=32;khi<64;khi+=2){
      cf v=Pmsh[khi][kw]; cf tt=tw[idx];
      ser += v.x*tt.x - v.y*tt.y; sei += v.x*tt.y + v.y*tt.x;
      idx=(idx+s2h)&127;
    }
    idx = h&127;
    for (int khi=1;khi<32;khi+=2){
      cf v=Pmsh[khi][kw]; cf tt=tw[idx];
      sor += v.x*tt.x - v.y*tt.y; soi += v.x*tt.y + v.y*tt.x;
      idx=(idx+s2h)&127;
    }
    idx = (97*h)&127;
    for (int khi=33;khi<64;khi+=2){
      cf v=Pmsh[khi][kw]; cf tt=tw[idx];
      sor += v.x*tt.x - v.y*tt.y; soi += v.x*tt.y + v.y*tt.x;
      idx=(idx+s2h)&127;
    }
    PmAsh[bl][kw]   = make_float2(ser+sor, sei+soi);
    PmAsh[8+bl][kw] = make_float2(ser-sor, sei-soi);
  }
  __syncthreads();
  float cst = consts;
  float s1=0.f, s2=0.f;
  const float* xb = x + b*32*16384;
  // irow: 256 thr = 16 hl x 16 wg; each: 4 base w (<64) -> 8 pixels
  {
    int hl = threadIdx.x>>4, wg = threadIdx.x&15;
    int w0 = wg*4;
    int gh = (hl<8)? hb+hl : hb+(hl-8)+64;
    int off = gh*128;
    float Se[4], So[4];
    #pragma unroll
    for (int j=0;j<4;++j){
      int w = w0+j;
      int s2w = (2*w)&127;
      float se=0.f, so=0.f;
      int idx=0;
      for (int kwp=0;kwp<16;++kwp){          // even kw = 2kwp
        cf v = PmAsh[hl][2*kwp]; cf tt=tw[idx];
        float term = v.x*tt.x - v.y*tt.y;
        se += (kwp? 2.f:1.f)*term;
        idx=(idx+s2w)&127;
      }
      idx = w&127;
      for (int kwp=0;kwp<16;++kwp){          // odd kw = 2kwp+1
        cf v = PmAsh[hl][2*kwp+1]; cf tt=tw[idx];
        so += 2.f*(v.x*tt.x - v.y*tt.y);
        idx=(idx+s2w)&127;
      }
      Se[j]=se; So[j]=so;
    }
    float mixa[4]={0,0,0,0}, mixb[4]={0,0,0,0};
    for (int s=0;s<32;++s){
      float m = Mrow[s];
      float4 xa = *(const float4*)(xb + s*16384 + off + w0);
      float4 xc = *(const float4*)(xb + s*16384 + off + w0 + 64);
      mixa[0]=fmaf(m,xa.x,mixa[0]); mixa[1]=fmaf(m,xa.y,mixa[1]);
      mixa[2]=fmaf(m,xa.z,mixa[2]); mixa[3]=fmaf(m,xa.w,mixa[3]);
      mixb[0]=fmaf(m,xc.x,mixb[0]); mixb[1]=fmaf(m,xc.y,mixb[1]);
      mixb[2]=fmaf(m,xc.z,mixb[2]); mixb[3]=fmaf(m,xc.w,mixb[3]);
    }
    float oa[4], ob[4];
    #pragma unroll
    for (int j=0;j<4;++j){
      oa[j] = cst + Se[j] + So[j] + mixa[j];
      ob[j] = cst + Se[j] - So[j] + mixb[j];
      s1 += oa[j]+ob[j];
      s2 += oa[j]*oa[j] + ob[j]*ob[j];
    }
    *(float4*)(z + n*16384 + off + w0)      = make_float4(oa[0],oa[1],oa[2],oa[3]);
    *(float4*)(z + n*16384 + off + w0 + 64) = make_float4(ob[0],ob[1],ob[2],ob[3]);
  }
  breduce2(s1,s2);
  if (threadIdx.x==0){ atomicAdd(&stats[n*2],s1); atomicAdd(&stats[n*2+1],s2); }
}

// an pointwise + row DFT (radix-2) -> Tm ; grid (64,8)
__global__ __launch_bounds__(256) void k_rfft_row_an(const float* __restrict__ z, const float* __restrict__ statsZ,
                              const float* __restrict__ ng, const float* __restrict__ nb,
                              float* __restrict__ Tm){
  __shared__ float tile[16][128];
  __shared__ cf tw[128];
  init_tw(tw,128,-1.f);
  int n=blockIdx.x, h0=blockIdx.y*16;
  float S=statsZ[n*2], S2=statsZ[n*2+1];
  float mz=S*(1.f/16384.f), vz=S2*(1.f/16384.f)-mz*mz;
  float az=rsqrtf(vz+EPSV);
  float g1=ng[1], g2=ng[2], b2v=nb[2];
  float vat = g1*g1*vz*az*az;
  float C1 = az*g1*rsqrtf(vat+EPSV)*g2;
  float Dc = b2v - mz*C1;
  for (int i=threadIdx.x;i<2048;i+=256)
    tile[i>>7][i&127] = fmaf(z[n*16384+h0*128+i], C1, Dc);
  __syncthreads();
  for (int i=threadIdx.x;i<1024;i+=256){
    int hl=i>>6, w=i&63;
    float a=tile[hl][w], b=tile[hl][w+64];
    tile[hl][w]=a+b; tile[hl][w+64]=a-b;
  }
  __syncthreads();
  for (int i=threadIdx.x;i<512;i+=256){
    int hl=i>>5, kw=i&31;
    int sel = (kw&1)? 64 : 0;
    float re=0.f,im=0.f; int idx=0;
    for (int w=0;w<64;++w){
      float v=tile[hl][sel+w]; cf t=tw[idx];
      re=fmaf(v,t.x,re); im=fmaf(v,t.y,im);
      idx=(idx+kw)&127;
    }
    float* d = Tm + ((n*128+h0+hl)*32+kw)*2;
    d[0]=re*(1.f/16384.f); d[1]=im*(1.f/16384.f);
  }
}

// fused fwd col DFT + weight + inverse col DFT (radix-2 both); grid (64,4)
__global__ __launch_bounds__(256) void k_colpair(const float* __restrict__ Tm, const float* __restrict__ wM,
                                                 float* __restrict__ Am){
  __shared__ cf Tsh[128][9];
  __shared__ cf Gsh[64][9];
  __shared__ cf tw[128];
  init_tw(tw,128,-1.f);
  int n = blockIdx.x, kw8 = blockIdx.y*8;
  for (int i=threadIdx.x;i<1024;i+=256){
    int h=i>>3, kwl=i&7;
    Tsh[h][kwl] = ldc(Tm + ((n*128+h)*32 + kw8+kwl)*2);
  }
  __syncthreads();
  for (int i=threadIdx.x;i<512;i+=256){
    int h=i>>3, kwl=i&7;
    cf a=Tsh[h][kwl], b=Tsh[h+64][kwl];
    Tsh[h][kwl]    = make_float2(a.x+b.x, a.y+b.y);
    Tsh[h+64][kwl] = make_float2(a.x-b.x, a.y-b.y);
  }
  __syncthreads();
  {
    int kwl = threadIdx.x&7, base = threadIdx.x>>3;
    for (int r=0;r<2;++r){
      int khi = r*32 + base;
      int khF = (khi<32)? khi : khi+64;
      int sel = (khi&1)? 64 : 0;
      float re=0.f, im=0.f; int idx=0;
      for (int j=0;j<64;++j){
        cf v=Tsh[sel+j][kwl]; cf t=tw[idx];
        re += v.x*t.x - v.y*t.y; im += v.x*t.y + v.y*t.x;
        idx=(idx+khF)&127;
      }
      int half=(khi>=32)?1:0, mr=khi&31;
      cf wv = ldc(wM + ((half*32+mr)*32 + kw8+kwl)*2);
      Gsh[khi][kwl] = cmul(make_float2(re,im), wv);
    }
  }
  __syncthreads();
  {
    int kwl = threadIdx.x&7, base = threadIdx.x>>3;
    for (int r=0;r<2;++r){
      int h = r*32 + base;                 // 0..63 ; outputs h and h+64
      float ser=0.f, sei=0.f, sor=0.f, soi=0.f;
      int s2h = (2*h)&127;
      int idx=0;
      for (int khi=0;khi<32;khi+=2){
        cf v=Gsh[khi][kwl]; cf t=tw[idx];
        ser += v.x*t.x + v.y*t.y; sei += v.y*t.x - v.x*t.y;
        idx=(idx+s2h)&127;
      }
      idx=(96*h)&127;
      for (int khi=32;khi<64;khi+=2){
        cf v=Gsh[khi][kwl]; cf t=tw[idx];
        ser += v.x*t.x + v.y*t.y; sei += v.y*t.x - v.x*t.y;
        idx=(idx+s2h)&127;
      }
      idx=h&127;
      for (int khi=1;khi<32;khi+=2){
        cf v=Gsh[khi][kwl]; cf t=tw[idx];
        sor += v.x*t.x + v.y*t.y; soi += v.y*t.x - v.x*t.y;
        idx=(idx+s2h)&127;
      }
      idx=(97*h)&127;
      for (int khi=33;khi<64;khi+=2){
        cf v=Gsh[khi][kwl]; cf t=tw[idx];
        sor += v.x*t.x + v.y*t.y; soi += v.y*t.x - v.x*t.y;
        idx=(idx+s2h)&127;
      }
      stc(Am + ((n*128+h)*32 + kw8+kwl)*2,    make_float2(ser+sor, sei+soi));
      stc(Am + ((n*128+h+64)*32 + kw8+kwl)*2, make_float2(ser-sor, sei-soi));
    }
  }
}

// irfft row (radix-2 on w pairs); writes spatial + stats; grid (64,8)
__global__ __launch_bounds__(256) void k_mirfft_row(const float* __restrict__ Am, float* __restrict__ out,
                                                    float* __restrict__ stats){
  __shared__ cf rowA[16][33];
  __shared__ cf tw[128];
  init_tw(tw,128,1.f);
  int n=blockIdx.x, h0=blockIdx.y*16;
  for (int i=threadIdx.x;i<512;i+=256){
    int hl=i>>5, kw=i&31;
    rowA[hl][kw] = ldc(Am + ((n*128+h0+hl)*32+kw)*2);
  }
  __syncthreads();
  float s=0.f,s2=0.f;
  for (int i=threadIdx.x;i<1024;i+=256){
    int hl=i>>6, w=i&63;
    int s2w = (2*w)&127;
    float se=0.f, so=0.f;
    int idx=0;
    for (int kwp=0;kwp<16;++kwp){
      cf v=rowA[hl][2*kwp]; cf t=tw[idx];
      float term=v.x*t.x-v.y*t.y;
      se += (kwp? 2.f:1.f)*term;
      idx=(idx+s2w)&127;
    }
    idx = w&127;
    for (int kwp=0;kwp<16;++kwp){
      cf v=rowA[hl][2*kwp+1]; cf t=tw[idx];
      so += 2.f*(v.x*t.x-v.y*t.y);
      idx=(idx+s2w)&127;
    }
    float oa = se+so, ob = se-so;
    out[n*16384+(h0+hl)*128+w]    = oa;
    out[n*16384+(h0+hl)*128+w+64] = ob;
    s+=oa+ob; s2 += oa*oa + ob*ob;
  }
  breduce2(s,s2);
  if (threadIdx.x==0){ atomicAdd(&stats[n*2],s); atomicAdd(&stats[n*2+1],s2); }
}

// m0 = gelu(...); writes m0 and M1's rfft-row (radix-2)
__global__ __launch_bounds__(256) void k_m0_rfft_row(const float* __restrict__ fno, const float* __restrict__ z,
                              const float* __restrict__ stats0, const float* __restrict__ statsZ,
                              const float* __restrict__ ng, const float* __restrict__ nb,
                              const float* __restrict__ wM0s, const float* __restrict__ bM0s,
                              float* __restrict__ m0out, float* __restrict__ Tm){
  __shared__ float tile[16][128];
  __shared__ cf tw[128];
  init_tw(tw,128,-1.f);
  int n=blockIdx.x, h0=blockIdx.y*16;
  float S0=stats0[n*2], S02=stats0[n*2+1];
  float m0m=S0*(1.f/16384.f), v0=S02*(1.f/16384.f)-m0m*m0m;
  float A0=rsqrtf(v0+EPSV)*ng[3];
  float B0=nb[3]-m0m*A0;
  float Sz=statsZ[n*2], Sz2=statsZ[n*2+1];
  float mz=Sz*(1.f/16384.f), vz=Sz2*(1.f/16384.f)-mz*mz;
  float az=rsqrtf(vz+EPSV);
  float g1=ng[1], g2=ng[2];
  float vat=g1*g1*vz*az*az;
  float C1=az*g1*rsqrtf(vat+EPSV)*g2;
  float Dc=nb[2]-mz*C1;
  float ws_=wM0s[0], bs_=bM0s[0];
  for (int i=threadIdx.x;i<2048;i+=256){
    int gi = n*16384 + h0*128 + i;
    float nf = fmaf(fno[gi], A0, B0);
    float an = fmaf(z[gi], C1, Dc);
    float pre = nf + fmaf(ws_, an, bs_);
    float gv = 0.5f*pre*(1.f+erff(pre*0.70710678118654752f));
    tile[i>>7][i&127]=gv;
    m0out[gi]=gv;
  }
  __syncthreads();
  for (int i=threadIdx.x;i<1024;i+=256){
    int hl=i>>6, w=i&63;
    float a=tile[hl][w], b=tile[hl][w+64];
    tile[hl][w]=a+b; tile[hl][w+64]=a-b;
  }
  __syncthreads();
  for (int i=threadIdx.x;i<512;i+=256){
    int hl=i>>5, kw=i&31;
    int sel = (kw&1)? 64:0;
    float re=0.f,im=0.f; int idx=0;
    for (int w=0;w<64;++w){
      float v=tile[hl][sel+w]; cf t=tw[idx];
      re=fmaf(v,t.x,re); im=fmaf(v,t.y,im);
      idx=(idx+kw)&127;
    }
    float* d = Tm + ((n*128+h0+hl)*32+kw)*2;
    d[0]=re*(1.f/16384.f); d[1]=im*(1.f/16384.f);
  }
}

// m1 = inorm(fno1)*g4+b4 + wM1s*m0 + bM1s; stats2
__global__ __launch_bounds__(256) void k_m1_mix(const float* fno1, const float* __restrict__ m0,
                         const float* __restrict__ stats1, const float* __restrict__ ng, const float* __restrict__ nb,
                         const float* __restrict__ wM1s, const float* __restrict__ bM1s,
                         float* m1out, float* __restrict__ stats2){
  int n=blockIdx.x, h0=blockIdx.y*16;
  float S=stats1[n*2], S2v=stats1[n*2+1];
  float m1m=S*(1.f/16384.f), v1=S2v*(1.f/16384.f)-m1m*m1m;
  float A1=rsqrtf(v1+EPSV)*ng[4];
  float Bc1=nb[4]-m1m*A1;
  float ws_=wM1s[0], bs_=bM1s[0];
  float s=0.f,s2=0.f;
  for (int i=threadIdx.x;i<2048;i+=256){
    int gi=n*16384+h0*128+i;
    float v = fmaf(fno1[gi],A1,Bc1) + fmaf(ws_,m0[gi],bs_);
    m1out[gi]=v;
    s+=v; s2=fmaf(v,v,s2);
  }
  breduce2(s,s2);
  if (threadIdx.x==0){ atomicAdd(&stats2[n*2],s); atomicAdd(&stats2[n*2+1],s2); }
}

// out = inorm(m1)*g5+b5 + attention
__global__ __launch_bounds__(256) void k_final(const float* __restrict__ m1, const float* __restrict__ z,
                        const float* __restrict__ stats2, const float* __restrict__ statsZ,
                        const float* __restrict__ ng, const float* __restrict__ nb,
                        float* __restrict__ out){
  int n=blockIdx.x, h0=blockIdx.y*16;
  float S=stats2[n*2], S2v=stats2[n*2+1];
  float mm=S*(1.f/16384.f), vv=S2v*(1.f/16384.f)-mm*mm;
  float A2=rsqrtf(vv+EPSV)*ng[5];
  float B2c=nb[5]-mm*A2;
  float Sz=statsZ[n*2], Sz2=statsZ[n*2+1];
  float mz=Sz*(1.f/16384.f), vz=Sz2*(1.f/16384.f)-mz*mz;
  float Az=rsqrtf(vz+EPSV)*ng[1];
  float Bz=nb[1]-mz*Az;
  for (int i=threadIdx.x;i<2048;i+=256){
    int gi=n*16384+h0*128+i;
    out[gi] = fmaf(m1[gi],A2,B2c) + fmaf(z[gi],Az,Bz);
  }
}

// ---------------------------------------------------------------------------
extern "C" void kernel_launch(void* const* d_in, const int* in_sizes, int n_in,
                              void* d_out, int out_size, void* d_ws, size_t ws_size,
                              hipStream_t stream){
  (void)in_sizes; (void)n_in; (void)out_size; (void)ws_size;
  const float* x   = (const float*)d_in[0];
  const float* wK  = (const float*)d_in[1];
  const float* wKs = (const float*)d_in[2];
  const float* bKs = (const float*)d_in[3];
  const float* wQ  = (const float*)d_in[4];
  const float* wQs = (const float*)d_in[5];
  const float* bQs = (const float*)d_in[6];
  const float* wV  = (const float*)d_in[7];
  const float* wVs = (const float*)d_in[8];
  const float* bVs = (const float*)d_in[9];
  const float* wP  = (const float*)d_in[10];
  const float* wPs = (const float*)d_in[11];
  const float* bPs = (const float*)d_in[12];
  const float* wM0 = (const float*)d_in[13];
  const float* wM0s= (const float*)d_in[14];
  const float* bM0s= (const float*)d_in[15];
  const float* wM1 = (const float*)d_in[16];
  const float* wM1s= (const float*)d_in[17];
  const float* bM1s= (const float*)d_in[18];
  const float* ng  = (const float*)d_in[19];
  const float* nb  = (const float*)d_in[20];
  float* out = (float*)d_out;
  float* ws  = (float*)d_ws;

  float* F      = ws;                     //   270,336
  float* Cw     = F + 270336;             //   540,672
  float* scoreP = Cw + 540672;            // 2,097,152
  float* attn   = scoreP + 2097152;       //    65,536
  float* stats  = attn + 65536;           //       512
  float* Pm     = stats + 512;            //   262,144
  float* gcons  = Pm + 262144;            //       128
  float* gam    = gcons + 128;            //   135,168
  float* normAB = gam + 135168;           //       128
  float* z      = normAB + 128;           // 1,048,576
  float* m0b    = z + 1048576;            // 1,048,576
  float* fx     = m0b + 1048576;          // 1,048,576
  float* Tm     = fx + 1048576;           //   524,288
  float* Am     = Tm + 524288;            //   524,288
  float* statsZ = stats;
  float* stats0 = stats + 128;
  float* stats1 = stats + 256;
  float* stats2 = stats + 384;

  k_gamma_xstats<<<96,256,0,stream>>>(wQ,wQs,bQs, wK,wKs,bKs, x, ng, nb, gam, gcons, stats, normAB);
  k_rfft_row_x<<<dim3(64,8),256,0,stream>>>(x, normAB, Cw);
  k_fcol<<<dim3(64,9),256,0,stream>>>(Cw, F);
  k_score<<<dim3(32,2,8),256,0,stream>>>(F, gam, scoreP);
  k_softmax<<<dim3(2,32),1024,0,stream>>>(attn, F, gcons, scoreP);
  k_pmode<<<dim3(2,64,4),256,0,stream>>>(F, attn, wV, wVs, wP, wPs, Pm);
  k_zmix<<<dim3(64,8),256,0,stream>>>(x, Pm, attn, normAB, wVs, wPs, wP, bPs, bVs, z, statsZ);
  k_rfft_row_an<<<dim3(64,8),256,0,stream>>>(z, statsZ, ng, nb, Tm);
  k_colpair<<<dim3(64,4),256,0,stream>>>(Tm, wM0, Am);
  k_mirfft_row<<<dim3(64,8),256,0,stream>>>(Am, fx, stats0);
  k_m0_rfft_row<<<dim3(64,8),256,0,stream>>>(fx, z, stats0, statsZ, ng, nb, wM0s, bM0s, m0b, Tm);
  k_colpair<<<dim3(64,4),256,0,stream>>>(Tm, wM1, Am);
  k_mirfft_row<<<dim3(64,8),256,0,stream>>>(Am, fx, stats1);
  k_m1_mix<<<dim3(64,8),256,0,stream>>>(fx, m0b, stats1, ng, nb, wM1s, bM1s, fx, stats2);
  k_final<<<dim3(64,8),256,0,stream>>>(fx, z, stats2, statsZ, ng, nb, out);
}